// Round 1
// baseline (521.539 us; speedup 1.0000x reference)
//
#include <hip/hip_runtime.h>
#include <math.h>

#define NHEAD 8
#define BATCH 4
#define NN 1024              // H*W
#define MM 21
#define DD 84                // M*hd
#define BN (BATCH*NHEAD)     // 32
#define NROWS (BATCH*NN*MM)  // 86016

// ---------------- Kernel A: qkv projection + scatter to (B,nh,N,84) ----------------
__global__ __launch_bounds__(256)
void qkv_kernel(const float* __restrict__ x, const float* __restrict__ Wq,
                const float* __restrict__ bq, float* __restrict__ qb,
                float* __restrict__ kb, float* __restrict__ vb)
{
    __shared__ __align__(16) float xs[32*36];
    __shared__ __align__(16) float wq[32*96];
    __shared__ float bqs[96];
    int t = threadIdx.x;
    int R0 = blockIdx.x * 32;
    for (int i = t; i < 3072; i += 256) wq[i] = Wq[i];
    if (t < 96) bqs[t] = bq[t];
    const float* xb = x + (size_t)R0 * 32;
    for (int i = t; i < 1024; i += 256)
        xs[(i >> 5) * 36 + (i & 31)] = xb[i];
    __syncthreads();

    int row = t >> 3;
    int cj  = t & 7;           // owns cols cj*12 .. cj*12+11
    float acc[12];
#pragma unroll
    for (int cc = 0; cc < 12; cc++) acc[cc] = bqs[cj*12 + cc];
    const float4* xr = (const float4*)(xs + row*36);
#pragma unroll
    for (int k4 = 0; k4 < 8; k4++) {
        float4 xa = xr[k4];
        float xv[4] = {xa.x, xa.y, xa.z, xa.w};
#pragma unroll
        for (int u = 0; u < 4; u++) {
            int kk = k4*4 + u;
            const float4* wr = (const float4*)(wq + kk*96 + cj*12);
            float4 w0 = wr[0], w1 = wr[1], w2 = wr[2];
            acc[0] += xv[u]*w0.x; acc[1]  += xv[u]*w0.y; acc[2]  += xv[u]*w0.z; acc[3]  += xv[u]*w0.w;
            acc[4] += xv[u]*w1.x; acc[5]  += xv[u]*w1.y; acc[6]  += xv[u]*w1.z; acc[7]  += xv[u]*w1.w;
            acc[8] += xv[u]*w2.x; acc[9]  += xv[u]*w2.y; acc[10] += xv[u]*w2.z; acc[11] += xv[u]*w2.w;
        }
    }
    int R = R0 + row;
    int b_ = R / 21;
    int m  = R - b_*21;
    int b  = b_ >> 10;
    int n  = b_ & 1023;
#pragma unroll
    for (int cc = 0; cc < 12; cc++) {
        int col = cj*12 + cc;
        int s   = col >> 5;
        int c   = col & 31;
        int hh  = c >> 2, dd2 = c & 3;
        float* dst = (s == 0) ? qb : (s == 1) ? kb : vb;
        dst[(((size_t)(b*NHEAD + hh))*NN + n)*DD + m*4 + dd2] = acc[cc];
    }
}

// ---------------- Kernel B: x2[b,h,n] = x row . W_sq + b_sq ----------------
__global__ __launch_bounds__(256)
void x2_kernel(const float* __restrict__ x, const float* __restrict__ Wsq,
               const float* __restrict__ bsq, float* __restrict__ x2)
{
    __shared__ __align__(16) float ws[84];
    int t = threadIdx.x;
    if (t < 84) ws[t] = Wsq[t];
    __syncthreads();
    int i = blockIdx.x * 256 + t;        // 0..32767 : (b*8+h)*1024 + n
    int b = i >> 13;
    int h = (i >> 10) & 7;
    int n = i & 1023;
    const float* xr = x + ((size_t)(b*NN + n))*672 + h*4;   // 21*32=672
    float acc = bsq[0];
#pragma unroll
    for (int m = 0; m < 21; m++) {
        float4 xv = *(const float4*)(xr + m*32);
        float4 wv = *(const float4*)(ws + m*4);
        acc += xv.x*wv.x + xv.y*wv.y + xv.z*wv.z + xv.w*wv.w;
    }
    x2[i] = acc;
}

// ---------------- Kernel C: per-(b,h) avg+max pool ----------------
__global__ __launch_bounds__(256)
void pool_kernel(const float* __restrict__ x2, float* __restrict__ spool)
{
    int bh = blockIdx.x;   // 0..31
    int t = threadIdx.x;
    const float* p = x2 + (size_t)bh*NN;
    float s = 0.f, mx = -INFINITY;
    for (int i = t; i < NN; i += 256) { float v = p[i]; s += v; mx = fmaxf(mx, v); }
#pragma unroll
    for (int off = 1; off < 64; off <<= 1) {
        s  += __shfl_xor(s, off);
        mx  = fmaxf(mx, __shfl_xor(mx, off));
    }
    __shared__ float rs[4], rm[4];
    int w = t >> 6;
    if ((t & 63) == 0) { rs[w] = s; rm[w] = mx; }
    __syncthreads();
    if (t == 0) {
        float ss = rs[0]+rs[1]+rs[2]+rs[3];
        float mm = fmaxf(fmaxf(rm[0],rm[1]), fmaxf(rm[2],rm[3]));
        spool[bh] = ss * (1.f/1024.f) + mm;
    }
}

// ---------------- Kernel D: depthwise conv + pooled, batch-mean -> xw, xp ----------------
__global__ __launch_bounds__(256)
void lspe_kernel(const float* __restrict__ x2, const float* __restrict__ spool,
                 const float* __restrict__ Wdw, const float* __restrict__ bdw,
                 float* __restrict__ xw, float* __restrict__ xp)
{
    int i = blockIdx.x*256 + threadIdx.x;   // 0..8191 : h*1024 + n
    int h = i >> 10;
    int n = i & 1023;
    int y = n >> 5, xx = n & 31;
    int g0 = h >> 1;   // conv group of output channel o=h ; o2=8+h uses 4+g0
    float accW = 0.f, accP = 0.f;
    for (int b = 0; b < 4; b++) {
        float sp = spool[b*8 + h];
        float c0 = bdw[h], c1 = bdw[8 + h];
        const float* a0 = x2 + (size_t)(b*8 + g0)*NN;
        const float* a1 = x2 + (size_t)(b*8 + 4 + g0)*NN;
#pragma unroll
        for (int ky = 0; ky < 3; ky++) {
            int yy = y + ky - 1;
            if (yy < 0 || yy > 31) continue;
#pragma unroll
            for (int kx = 0; kx < 3; kx++) {
                int xc = xx + kx - 1;
                if (xc < 0 || xc > 31) continue;
                c0 += a0[yy*32 + xc] * Wdw[h*9 + ky*3 + kx];
                c1 += a1[yy*32 + xc] * Wdw[(8+h)*9 + ky*3 + kx];
            }
        }
        accW += c0 + sp;
        accP += c1 + sp;
    }
    xw[i] = 0.25f * accW;
    xp[i] = 0.25f * accP;
}

// ---------------- Kernel E: full-padding correlation -> 63x63 bias table per head ----------------
__global__ __launch_bounds__(256)
void bias_kernel(const float* __restrict__ xw, const float* __restrict__ xp,
                 float* __restrict__ btab)
{
    __shared__ float sxw[1024], sxp[1024];
    int h = blockIdx.y;
    int t = threadIdx.x;
    for (int i = t; i < 1024; i += 256) { sxw[i] = xw[h*1024+i]; sxp[i] = xp[h*1024+i]; }
    __syncthreads();
    int p = blockIdx.x*256 + t;
    if (p >= 3969) return;
    int oy = p / 63, ox = p - oy*63;
    int alo = max(0, oy-31), ahi = min(31, oy);
    int clo = max(0, ox-31), chi = min(31, ox);
    float acc = 0.f;
    for (int a = alo; a <= ahi; a++)
        for (int c = clo; c <= chi; c++)
            acc += sxp[a*32 + c] * sxw[(oy-a)*32 + (ox-c)];
    btab[h*3969 + p] = acc;
}

// ---------------- Kernel F: flash attention with LDS bias table ----------------
#define SD 100
__global__ __launch_bounds__(256, 2)
void attn_kernel(const float* __restrict__ q, const float* __restrict__ k,
                 const float* __restrict__ v, const float* __restrict__ btab_g,
                 float* __restrict__ Obuf)
{
    __shared__ __align__(16) float qs[64*SD];
    __shared__ __align__(16) float ks[32*SD];
    __shared__ __align__(16) float vs[32*SD];
    __shared__ float ps[64*33];
    __shared__ float btab[3969];

    int t = threadIdx.x;
    int bid = blockIdx.x;
    int qt = bid & 15;
    int bh = bid >> 4;
    int h = bh & 7;
    int q0 = qt * 64;

    const float* qbase = q + ((size_t)bh*NN + q0)*DD;
    for (int i = t; i < 64*DD; i += 256) {
        int r = i / DD, d = i - r*DD;
        qs[r*SD + d] = qbase[i];
    }
    const float* bt = btab_g + h*3969;
    for (int i = t; i < 3969; i += 256) btab[i] = bt[i];

    int r2 = t >> 3, tj = t & 7;
    int nq0 = q0 + r2, nq1 = q0 + r2 + 32;
    int y0 = nq0 >> 5, x0c = nq0 & 31;
    int y1 = nq1 >> 5, x1c = nq1 & 31;

    float o0[12], o1[12];
#pragma unroll
    for (int d = 0; d < 12; d++) { o0[d] = 0.f; o1[d] = 0.f; }
    float m0 = -INFINITY, m1 = -INFINITY, l0 = 0.f, l1 = 0.f;
    const float scale = 0.03125f;   // N^-0.5 = 1/32

    for (int kt = 0; kt < 32; kt++) {
        __syncthreads();
        const float* kbp = k + ((size_t)bh*NN + kt*32)*DD;
        const float* vbp = v + ((size_t)bh*NN + kt*32)*DD;
        for (int i = t; i < 32*DD; i += 256) {
            int r = i / DD, d = i - r*DD;
            ks[r*SD + d] = kbp[i];
            vs[r*SD + d] = vbp[i];
        }
        for (int i = t; i < 32*12; i += 256) {
            int r = i / 12, d = 84 + (i - r*12);
            vs[r*SD + d] = 0.f;
        }
        __syncthreads();

        // ---- S = scale * q.k + bias ----
        float s0[4] = {0,0,0,0}, s1[4] = {0,0,0,0};
        const float4* qr0 = (const float4*)(qs + r2*SD);
        const float4* qr1 = (const float4*)(qs + (r2+32)*SD);
        for (int c = 0; c < 21; c++) {
            float4 qa = qr0[c];
            float4 qbv = qr1[c];
#pragma unroll
            for (int jj = 0; jj < 4; jj++) {
                float4 kv = ((const float4*)(ks + (tj + 8*jj)*SD))[c];
                s0[jj] += qa.x*kv.x + qa.y*kv.y + qa.z*kv.z + qa.w*kv.w;
                s1[jj] += qbv.x*kv.x + qbv.y*kv.y + qbv.z*kv.z + qbv.w*kv.w;
            }
        }
        float sb0[4], sb1[4];
#pragma unroll
        for (int jj = 0; jj < 4; jj++) {
            int nk = kt*32 + tj + 8*jj;
            int ky = nk >> 5, kx = nk & 31;
            sb0[jj] = s0[jj]*scale + btab[(y0 - ky + 31)*63 + (x0c - kx + 31)];
            sb1[jj] = s1[jj]*scale + btab[(y1 - ky + 31)*63 + (x1c - kx + 31)];
        }

        // ---- online softmax (8 lanes per row cooperate) ----
        float mt0 = fmaxf(fmaxf(sb0[0], sb0[1]), fmaxf(sb0[2], sb0[3]));
        float mt1 = fmaxf(fmaxf(sb1[0], sb1[1]), fmaxf(sb1[2], sb1[3]));
#pragma unroll
        for (int off = 1; off < 8; off <<= 1) {
            mt0 = fmaxf(mt0, __shfl_xor(mt0, off));
            mt1 = fmaxf(mt1, __shfl_xor(mt1, off));
        }
        float mn0 = fmaxf(m0, mt0);
        float mn1 = fmaxf(m1, mt1);
        float alpha0 = __expf(m0 - mn0);
        float alpha1 = __expf(m1 - mn1);
        float p0[4], p1[4];
        float sum0 = 0.f, sum1 = 0.f;
#pragma unroll
        for (int jj = 0; jj < 4; jj++) {
            p0[jj] = __expf(sb0[jj] - mn0); sum0 += p0[jj];
            p1[jj] = __expf(sb1[jj] - mn1); sum1 += p1[jj];
        }
#pragma unroll
        for (int off = 1; off < 8; off <<= 1) {
            sum0 += __shfl_xor(sum0, off);
            sum1 += __shfl_xor(sum1, off);
        }
        l0 = l0*alpha0 + sum0; m0 = mn0;
        l1 = l1*alpha1 + sum1; m1 = mn1;
#pragma unroll
        for (int d = 0; d < 12; d++) { o0[d] *= alpha0; o1[d] *= alpha1; }
#pragma unroll
        for (int jj = 0; jj < 4; jj++) {
            ps[r2*33 + tj + 8*jj]      = p0[jj];
            ps[(r2+32)*33 + tj + 8*jj] = p1[jj];
        }
        __syncthreads();

        // ---- O += P @ V  (thread owns d = tj*12 .. tj*12+11) ----
        for (int j = 0; j < 32; j++) {
            float pa = ps[r2*33 + j];
            float pb = ps[(r2+32)*33 + j];
            const float4* vr = (const float4*)(vs + j*SD + tj*12);
            float4 va = vr[0], vb2 = vr[1], vc = vr[2];
            o0[0] += pa*va.x;  o0[1] += pa*va.y;  o0[2]  += pa*va.z;  o0[3]  += pa*va.w;
            o0[4] += pa*vb2.x; o0[5] += pa*vb2.y; o0[6]  += pa*vb2.z; o0[7]  += pa*vb2.w;
            o0[8] += pa*vc.x;  o0[9] += pa*vc.y;  o0[10] += pa*vc.z;  o0[11] += pa*vc.w;
            o1[0] += pb*va.x;  o1[1] += pb*va.y;  o1[2]  += pb*va.z;  o1[3]  += pb*va.w;
            o1[4] += pb*vb2.x; o1[5] += pb*vb2.y; o1[6]  += pb*vb2.z; o1[7]  += pb*vb2.w;
            o1[8] += pb*vc.x;  o1[9] += pb*vc.y;  o1[10] += pb*vc.z;  o1[11] += pb*vc.w;
        }
    }

    float li0 = 1.f / l0, li1 = 1.f / l1;
    int dbase = tj*12;
    float* ob0 = Obuf + ((size_t)bh*NN + nq0)*DD;
    float* ob1 = Obuf + ((size_t)bh*NN + nq1)*DD;
#pragma unroll
    for (int d = 0; d < 12; d++) {
        int dd = dbase + d;
        if (dd < 84) { ob0[dd] = o0[d]*li0; ob1[dd] = o1[d]*li1; }
    }
}

// ---------------- Kernel G: gather heads + output projection ----------------
__global__ __launch_bounds__(256)
void proj_kernel(const float* __restrict__ Obuf, const float* __restrict__ Wp,
                 const float* __restrict__ bp, float* __restrict__ out)
{
    __shared__ __align__(16) float xs[32*36];
    __shared__ __align__(16) float wp[1024];
    __shared__ float bps[32];
    int t = threadIdx.x;
    int R0 = blockIdx.x * 32;
    for (int i = t; i < 1024; i += 256) wp[i] = Wp[i];
    if (t < 32) bps[t] = bp[t];
    for (int i = t; i < 1024; i += 256) {
        int row = i >> 5, c = i & 31;
        int R = R0 + row;
        int b_ = R / 21, m = R - b_*21;
        int b = b_ >> 10, n = b_ & 1023;
        int hh = c >> 2, dd2 = c & 3;
        xs[row*36 + c] = Obuf[(((size_t)(b*NHEAD + hh))*NN + n)*DD + m*4 + dd2];
    }
    __syncthreads();
    int row = t >> 3, cj = t & 7;
    float acc[4];
#pragma unroll
    for (int cc = 0; cc < 4; cc++) acc[cc] = bps[cj*4 + cc];
    const float4* xr = (const float4*)(xs + row*36);
#pragma unroll
    for (int k4 = 0; k4 < 8; k4++) {
        float4 xa = xr[k4];
        float xv[4] = {xa.x, xa.y, xa.z, xa.w};
#pragma unroll
        for (int u = 0; u < 4; u++) {
            int kk = k4*4 + u;
            float4 w = *(const float4*)(wp + kk*32 + cj*4);
            acc[0] += xv[u]*w.x; acc[1] += xv[u]*w.y; acc[2] += xv[u]*w.z; acc[3] += xv[u]*w.w;
        }
    }
    *(float4*)(out + (size_t)(R0+row)*32 + cj*4) = make_float4(acc[0], acc[1], acc[2], acc[3]);
}

extern "C" void kernel_launch(void* const* d_in, const int* in_sizes, int n_in,
                              void* d_out, int out_size, void* d_ws, size_t ws_size,
                              hipStream_t stream)
{
    const float* x     = (const float*)d_in[0];
    const float* Wqkv  = (const float*)d_in[1];
    const float* bqkv  = (const float*)d_in[2];
    const float* Wproj = (const float*)d_in[3];
    const float* bproj = (const float*)d_in[4];
    const float* Wsq   = (const float*)d_in[5];
    const float* bsq   = (const float*)d_in[6];
    const float* Wdw   = (const float*)d_in[7];
    const float* bdw   = (const float*)d_in[8];

    float* ws = (float*)d_ws;
    const size_t QKV = (size_t)BN * NN * DD;    // 2,752,512 floats
    float* qbuf  = ws;
    float* kbuf  = qbuf + QKV;
    float* vbuf  = kbuf + QKV;
    float* Obuf  = vbuf + QKV;
    float* x2    = Obuf + QKV;
    float* spool = x2 + 32768;
    float* xw    = spool + 32;
    float* xp    = xw + 8192;
    float* btab  = xp + 8192;
    float* out   = (float*)d_out;

    qkv_kernel <<<NROWS/32, 256, 0, stream>>>(x, Wqkv, bqkv, qbuf, kbuf, vbuf);
    x2_kernel  <<<128,       256, 0, stream>>>(x, Wsq, bsq, x2);
    pool_kernel<<<32,        256, 0, stream>>>(x2, spool);
    lspe_kernel<<<32,        256, 0, stream>>>(x2, spool, Wdw, bdw, xw, xp);
    bias_kernel<<<dim3(16,8),256, 0, stream>>>(xw, xp, btab);
    attn_kernel<<<512,       256, 0, stream>>>(qbuf, kbuf, vbuf, btab, Obuf);
    proj_kernel<<<NROWS/32,  256, 0, stream>>>(Obuf, Wproj, bproj, out);
}

// Round 2
// 317.319 us; speedup vs baseline: 1.6436x; 1.6436x over previous
//
#include <hip/hip_runtime.h>
#include <math.h>

#define NHEAD 8
#define BATCH 4
#define NN 1024              // H*W
#define MM 21
#define DD 84                // M*hd
#define BN (BATCH*NHEAD)     // 32
#define NROWS (BATCH*NN*MM)  // 86016

typedef __attribute__((ext_vector_type(8))) short bf16x8;
typedef __attribute__((ext_vector_type(4))) float f32x4;

__device__ __forceinline__ unsigned short f2bf(float x) {
    union { float f; unsigned int u; } c; c.f = x;
    unsigned int r = (c.u + 0x7FFFu + ((c.u >> 16) & 1u)) >> 16;
    return (unsigned short)r;
}

// ---------------- Kernel A: qkv projection -> bf16 q,k ([bh][n][84]) and v^T ([bh][84][n]) ----------------
__global__ __launch_bounds__(256)
void qkv_kernel(const float* __restrict__ x, const float* __restrict__ Wq,
                const float* __restrict__ bq, ushort* __restrict__ qb,
                ushort* __restrict__ kb, ushort* __restrict__ vtb)
{
    __shared__ __align__(16) float xs[32*36];
    __shared__ __align__(16) float wq[32*96];
    __shared__ float bqs[96];
    int t = threadIdx.x;
    int R0 = blockIdx.x * 32;
    for (int i = t; i < 3072; i += 256) wq[i] = Wq[i];
    if (t < 96) bqs[t] = bq[t];
    const float* xb = x + (size_t)R0 * 32;
    for (int i = t; i < 1024; i += 256)
        xs[(i >> 5) * 36 + (i & 31)] = xb[i];
    __syncthreads();

    int row = t >> 3;
    int cj  = t & 7;           // owns cols cj*12 .. cj*12+11
    float acc[12];
#pragma unroll
    for (int cc = 0; cc < 12; cc++) acc[cc] = bqs[cj*12 + cc];
    const float4* xr = (const float4*)(xs + row*36);
#pragma unroll
    for (int k4 = 0; k4 < 8; k4++) {
        float4 xa = xr[k4];
        float xv[4] = {xa.x, xa.y, xa.z, xa.w};
#pragma unroll
        for (int u = 0; u < 4; u++) {
            int kk = k4*4 + u;
            const float4* wr = (const float4*)(wq + kk*96 + cj*12);
            float4 w0 = wr[0], w1 = wr[1], w2 = wr[2];
            acc[0] += xv[u]*w0.x; acc[1]  += xv[u]*w0.y; acc[2]  += xv[u]*w0.z; acc[3]  += xv[u]*w0.w;
            acc[4] += xv[u]*w1.x; acc[5]  += xv[u]*w1.y; acc[6]  += xv[u]*w1.z; acc[7]  += xv[u]*w1.w;
            acc[8] += xv[u]*w2.x; acc[9]  += xv[u]*w2.y; acc[10] += xv[u]*w2.z; acc[11] += xv[u]*w2.w;
        }
    }
    int R = R0 + row;
    int b_ = R / 21;
    int m  = R - b_*21;
    int b  = b_ >> 10;
    int n  = b_ & 1023;
#pragma unroll
    for (int cc = 0; cc < 12; cc++) {
        int col = cj*12 + cc;
        int s   = col >> 5;
        int c   = col & 31;
        int hh  = c >> 2, dd2 = c & 3;
        int bh  = b*NHEAD + hh;
        int d   = m*4 + dd2;
        ushort val = f2bf(acc[cc]);
        if (s == 0)      qb[((size_t)bh*NN + n)*DD + d] = val;
        else if (s == 1) kb[((size_t)bh*NN + n)*DD + d] = val;
        else             vtb[((size_t)bh*DD + d)*NN + n] = val;
    }
}

// ---------------- Kernel B: x2[b,h,n] = x row . W_sq + b_sq ----------------
__global__ __launch_bounds__(256)
void x2_kernel(const float* __restrict__ x, const float* __restrict__ Wsq,
               const float* __restrict__ bsq, float* __restrict__ x2)
{
    __shared__ __align__(16) float ws[84];
    int t = threadIdx.x;
    if (t < 84) ws[t] = Wsq[t];
    __syncthreads();
    int i = blockIdx.x * 256 + t;        // 0..32767 : (b*8+h)*1024 + n
    int b = i >> 13;
    int h = (i >> 10) & 7;
    int n = i & 1023;
    const float* xr = x + ((size_t)(b*NN + n))*672 + h*4;   // 21*32=672
    float acc = bsq[0];
#pragma unroll
    for (int m = 0; m < 21; m++) {
        float4 xv = *(const float4*)(xr + m*32);
        float4 wv = *(const float4*)(ws + m*4);
        acc += xv.x*wv.x + xv.y*wv.y + xv.z*wv.z + xv.w*wv.w;
    }
    x2[i] = acc;
}

// ---------------- Kernel C: per-(b,h) avg+max pool ----------------
__global__ __launch_bounds__(256)
void pool_kernel(const float* __restrict__ x2, float* __restrict__ spool)
{
    int bh = blockIdx.x;   // 0..31
    int t = threadIdx.x;
    const float* p = x2 + (size_t)bh*NN;
    float s = 0.f, mx = -INFINITY;
    for (int i = t; i < NN; i += 256) { float v = p[i]; s += v; mx = fmaxf(mx, v); }
#pragma unroll
    for (int off = 1; off < 64; off <<= 1) {
        s  += __shfl_xor(s, off);
        mx  = fmaxf(mx, __shfl_xor(mx, off));
    }
    __shared__ float rs[4], rm[4];
    int w = t >> 6;
    if ((t & 63) == 0) { rs[w] = s; rm[w] = mx; }
    __syncthreads();
    if (t == 0) {
        float ss = rs[0]+rs[1]+rs[2]+rs[3];
        float mm = fmaxf(fmaxf(rm[0],rm[1]), fmaxf(rm[2],rm[3]));
        spool[bh] = ss * (1.f/1024.f) + mm;
    }
}

// ---------------- Kernel D: depthwise conv + pooled, batch-mean -> xw, xp ----------------
__global__ __launch_bounds__(256)
void lspe_kernel(const float* __restrict__ x2, const float* __restrict__ spool,
                 const float* __restrict__ Wdw, const float* __restrict__ bdw,
                 float* __restrict__ xw, float* __restrict__ xp)
{
    int i = blockIdx.x*256 + threadIdx.x;   // 0..8191 : h*1024 + n
    int h = i >> 10;
    int n = i & 1023;
    int y = n >> 5, xx = n & 31;
    int g0 = h >> 1;
    float accW = 0.f, accP = 0.f;
    for (int b = 0; b < 4; b++) {
        float sp = spool[b*8 + h];
        float c0 = bdw[h], c1 = bdw[8 + h];
        const float* a0 = x2 + (size_t)(b*8 + g0)*NN;
        const float* a1 = x2 + (size_t)(b*8 + 4 + g0)*NN;
#pragma unroll
        for (int ky = 0; ky < 3; ky++) {
            int yy = y + ky - 1;
            if (yy < 0 || yy > 31) continue;
#pragma unroll
            for (int kx = 0; kx < 3; kx++) {
                int xc = xx + kx - 1;
                if (xc < 0 || xc > 31) continue;
                c0 += a0[yy*32 + xc] * Wdw[h*9 + ky*3 + kx];
                c1 += a1[yy*32 + xc] * Wdw[(8+h)*9 + ky*3 + kx];
            }
        }
        accW += c0 + sp;
        accP += c1 + sp;
    }
    xw[i] = 0.25f * accW;
    xp[i] = 0.25f * accP;
}

// ---------------- Kernel E: full-padding correlation -> 63x63 bias table per head ----------------
__global__ __launch_bounds__(256)
void bias_kernel(const float* __restrict__ xw, const float* __restrict__ xp,
                 float* __restrict__ btab)
{
    __shared__ float sxw[1024], sxp[1024];
    int h = blockIdx.y;
    int t = threadIdx.x;
    for (int i = t; i < 1024; i += 256) { sxw[i] = xw[h*1024+i]; sxp[i] = xp[h*1024+i]; }
    __syncthreads();
    int p = blockIdx.x*256 + t;
    if (p >= 3969) return;
    int oy = p / 63, ox = p - oy*63;
    int alo = max(0, oy-31), ahi = min(31, oy);
    int clo = max(0, ox-31), chi = min(31, ox);
    float acc = 0.f;
    for (int a = alo; a <= ahi; a++)
        for (int c = clo; c <= chi; c++)
            acc += sxp[a*32 + c] * sxw[(oy-a)*32 + (ox-c)];
    btab[h*3969 + p] = acc;
}

// ---------------- Kernel F: MFMA flash attention ----------------
// Per block: 64 q-rows (4 waves x 16), 16 k-tiles of 64 keys, D padded 84->96.
#define SKB 104   // qs/ks stride in bf16 (2-way bank aliasing only)
#define VST 72    // vt stride (keys)
#define PST 68    // ps stride
__global__ __launch_bounds__(256, 2)
void attn_kernel(const ushort* __restrict__ qg, const ushort* __restrict__ kg,
                 const ushort* __restrict__ vg, const float* __restrict__ btg,
                 float* __restrict__ Obuf)
{
    __shared__ __align__(16) ushort qs[64*SKB];
    __shared__ __align__(16) ushort ks[64*SKB];
    __shared__ __align__(16) ushort vt[96*VST];
    __shared__ __align__(16) ushort ps[64*PST];
    __shared__ float btab[3969];

    int t   = threadIdx.x;
    int bid = blockIdx.x;
    int qt  = bid & 15;
    int bh  = bid >> 4;
    int h   = bh & 7;
    int q0  = qt * 64;

    // bias table -> LDS
    const float* bt = btg + h*3969;
    for (int i = t; i < 3969; i += 256) btab[i] = bt[i];

    // zero pads (dims 84..95) for qs/ks/vt — written once, persists
    unsigned int* qsu = (unsigned int*)qs;
    unsigned int* ksu = (unsigned int*)ks;
    unsigned int* vtu = (unsigned int*)vt;
    for (int i = t; i < 384; i += 256) {
        int r = i/6, p = i%6;
        qsu[(r*SKB + 84)/2 + p] = 0u;
        ksu[(r*SKB + 84)/2 + p] = 0u;
    }
    for (int i = t; i < 432; i += 256) {
        int r = i/36, p = i%36;
        vtu[((84+r)*VST)/2 + p] = 0u;
    }

    // stage Q tile (64 rows x 84 bf16)
    const ushort* qrow = qg + ((size_t)bh*NN + q0)*DD;
    for (int i = t; i < 1344; i += 256) {       // 64*21 ushort4
        int r = i/21, p = i - r*21;
        *(ushort4*)(qs + r*SKB + p*4) = *(const ushort4*)(qrow + r*DD + p*4);
    }
    __syncthreads();

    int w    = t >> 6;
    int lane = t & 63;
    int col  = lane & 15;
    int quad = lane >> 4;

    // per-lane row constants (C-layout rows quad*4+r)
    int nqr[4], rowb[4];
#pragma unroll
    for (int r = 0; r < 4; r++) {
        int nq = q0 + w*16 + quad*4 + r;
        nqr[r]  = nq;
        rowb[r] = ((nq >> 5) + 31)*63 + (nq & 31) + 31;   // (yq+31)*63 + xq+31
    }

    // Q A-frags (loop-invariant)
    bf16x8 aq[3];
#pragma unroll
    for (int c = 0; c < 3; c++)
        aq[c] = *(const bf16x8*)(qs + (w*16 + col)*SKB + c*32 + quad*8);

    f32x4 of[6];
#pragma unroll
    for (int f = 0; f < 6; f++) of[f] = (f32x4){0.f,0.f,0.f,0.f};
    float mrow[4] = {-INFINITY,-INFINITY,-INFINITY,-INFINITY};
    float lrow[4] = {0.f,0.f,0.f,0.f};
    const float scale = 0.03125f;

    for (int kt = 0; kt < 16; kt++) {
        __syncthreads();
        // stage K tile (64x84) and V^T tile (84 x 64 keys)
        const ushort* krow = kg + ((size_t)bh*NN + kt*64)*DD;
        const ushort* vrow = vg + (size_t)bh*DD*NN + kt*64;
        for (int i = t; i < 1344; i += 256) {
            int r = i/21, p = i - r*21;
            *(ushort4*)(ks + r*SKB + p*4) = *(const ushort4*)(krow + r*DD + p*4);
        }
        for (int i = t; i < 1344; i += 256) {
            int d = i >> 4, p = i & 15;
            *(ushort4*)(vt + d*VST + p*4) = *(const ushort4*)(vrow + (size_t)d*NN + p*4);
        }
        __syncthreads();

        // ---- S = Q K^T (MFMA) ----
        f32x4 sc[4];
#pragma unroll
        for (int f = 0; f < 4; f++) {
            f32x4 c = (f32x4){0.f,0.f,0.f,0.f};
#pragma unroll
            for (int cc = 0; cc < 3; cc++) {
                bf16x8 b = *(const bf16x8*)(ks + (f*16 + col)*SKB + cc*32 + quad*8);
                c = __builtin_amdgcn_mfma_f32_16x16x32_bf16(aq[cc], b, c, 0, 0, 0);
            }
            sc[f] = c;
        }

        // ---- bias add ----
        float sfull[4][4];
#pragma unroll
        for (int f = 0; f < 4; f++) {
            int nk = kt*64 + f*16 + col;
            int kb_ = (nk >> 5)*63 + (nk & 31);
#pragma unroll
            for (int r = 0; r < 4; r++)
                sfull[f][r] = sc[f][r]*scale + btab[rowb[r] - kb_];
        }

        // ---- online softmax (16 lanes per row group) ----
        float al[4];
#pragma unroll
        for (int r = 0; r < 4; r++) {
            float v = fmaxf(fmaxf(sfull[0][r], sfull[1][r]), fmaxf(sfull[2][r], sfull[3][r]));
            v = fmaxf(v, __shfl_xor(v, 1));
            v = fmaxf(v, __shfl_xor(v, 2));
            v = fmaxf(v, __shfl_xor(v, 4));
            v = fmaxf(v, __shfl_xor(v, 8));
            float mn = fmaxf(mrow[r], v);
            float a  = __expf(mrow[r] - mn);
            mrow[r] = mn;
            float s = 0.f;
#pragma unroll
            for (int f = 0; f < 4; f++) {
                float p = __expf(sfull[f][r] - mn);
                sfull[f][r] = p;
                s += p;
            }
            s += __shfl_xor(s, 1); s += __shfl_xor(s, 2);
            s += __shfl_xor(s, 4); s += __shfl_xor(s, 8);
            lrow[r] = lrow[r]*a + s;
            al[r] = a;
        }

        // ---- P -> LDS (bf16), per-wave private region, no barrier needed ----
#pragma unroll
        for (int r = 0; r < 4; r++) {
            int ro = (w*16 + quad*4 + r)*PST + col;
#pragma unroll
            for (int f = 0; f < 4; f++) ps[ro + f*16] = f2bf(sfull[f][r]);
        }

        // rescale O
#pragma unroll
        for (int f = 0; f < 6; f++)
#pragma unroll
            for (int r = 0; r < 4; r++) of[f][r] *= al[r];

        // ---- P A-frags + PV MFMAs ----
        bf16x8 pa0 = *(const bf16x8*)(ps + (w*16 + col)*PST + quad*8);
        bf16x8 pa1 = *(const bf16x8*)(ps + (w*16 + col)*PST + 32 + quad*8);
#pragma unroll
        for (int f = 0; f < 6; f++) {
            bf16x8 b0 = *(const bf16x8*)(vt + (f*16 + col)*VST + quad*8);
            bf16x8 b1 = *(const bf16x8*)(vt + (f*16 + col)*VST + 32 + quad*8);
            of[f] = __builtin_amdgcn_mfma_f32_16x16x32_bf16(pa0, b0, of[f], 0, 0, 0);
            of[f] = __builtin_amdgcn_mfma_f32_16x16x32_bf16(pa1, b1, of[f], 0, 0, 0);
        }
    }

    // ---- epilogue ----
    float linv[4];
#pragma unroll
    for (int r = 0; r < 4; r++) linv[r] = 1.f / lrow[r];
#pragma unroll
    for (int f = 0; f < 6; f++) {
        int d = f*16 + col;
        if (d < DD) {
#pragma unroll
            for (int r = 0; r < 4; r++)
                Obuf[((size_t)bh*NN + nqr[r])*DD + d] = of[f][r]*linv[r];
        }
    }
}

// ---------------- Kernel G: gather heads + output projection ----------------
__global__ __launch_bounds__(256)
void proj_kernel(const float* __restrict__ Obuf, const float* __restrict__ Wp,
                 const float* __restrict__ bp, float* __restrict__ out)
{
    __shared__ __align__(16) float xs[32*36];
    __shared__ __align__(16) float wp[1024];
    __shared__ float bps[32];
    int t = threadIdx.x;
    int R0 = blockIdx.x * 32;
    for (int i = t; i < 1024; i += 256) wp[i] = Wp[i];
    if (t < 32) bps[t] = bp[t];
    for (int i = t; i < 1024; i += 256) {
        int row = i >> 5, c = i & 31;
        int R = R0 + row;
        int b_ = R / 21, m = R - b_*21;
        int b = b_ >> 10, n = b_ & 1023;
        int hh = c >> 2, dd2 = c & 3;
        xs[row*36 + c] = Obuf[(((size_t)(b*NHEAD + hh))*NN + n)*DD + m*4 + dd2];
    }
    __syncthreads();
    int row = t >> 3, cj = t & 7;
    float acc[4];
#pragma unroll
    for (int cc = 0; cc < 4; cc++) acc[cc] = bps[cj*4 + cc];
    const float4* xr = (const float4*)(xs + row*36);
#pragma unroll
    for (int k4 = 0; k4 < 8; k4++) {
        float4 xa = xr[k4];
        float xv[4] = {xa.x, xa.y, xa.z, xa.w};
#pragma unroll
        for (int u = 0; u < 4; u++) {
            int kk = k4*4 + u;
            float4 w = *(const float4*)(wp + kk*32 + cj*4);
            acc[0] += xv[u]*w.x; acc[1] += xv[u]*w.y; acc[2] += xv[u]*w.z; acc[3] += xv[u]*w.w;
        }
    }
    *(float4*)(out + (size_t)(R0+row)*32 + cj*4) = make_float4(acc[0], acc[1], acc[2], acc[3]);
}

extern "C" void kernel_launch(void* const* d_in, const int* in_sizes, int n_in,
                              void* d_out, int out_size, void* d_ws, size_t ws_size,
                              hipStream_t stream)
{
    const float* x     = (const float*)d_in[0];
    const float* Wqkv  = (const float*)d_in[1];
    const float* bqkv  = (const float*)d_in[2];
    const float* Wproj = (const float*)d_in[3];
    const float* bproj = (const float*)d_in[4];
    const float* Wsq   = (const float*)d_in[5];
    const float* bsq   = (const float*)d_in[6];
    const float* Wdw   = (const float*)d_in[7];
    const float* bdw   = (const float*)d_in[8];

    const size_t QKV = (size_t)BN * NN * DD;    // 2,752,512
    ushort* qb  = (ushort*)d_ws;
    ushort* kb  = qb + QKV;
    ushort* vtb = kb + QKV;
    float* Obuf = (float*)(vtb + QKV);          // byte offset 3*QKV*2, 16-aligned
    float* x2    = Obuf + QKV;
    float* spool = x2 + 32768;
    float* xw    = spool + 32;
    float* xp    = xw + 8192;
    float* btab  = xp + 8192;
    float* out   = (float*)d_out;

    qkv_kernel <<<NROWS/32, 256, 0, stream>>>(x, Wqkv, bqkv, qb, kb, vtb);
    x2_kernel  <<<128,       256, 0, stream>>>(x, Wsq, bsq, x2);
    pool_kernel<<<32,        256, 0, stream>>>(x2, spool);
    lspe_kernel<<<32,        256, 0, stream>>>(x2, spool, Wdw, bdw, xw, xp);
    bias_kernel<<<dim3(16,8),256, 0, stream>>>(xw, xp, btab);
    attn_kernel<<<512,       256, 0, stream>>>(qb, kb, vtb, btab, Obuf);
    proj_kernel<<<NROWS/32,  256, 0, stream>>>(Obuf, Wproj, bproj, out);
}

// Round 3
// 256.341 us; speedup vs baseline: 2.0346x; 1.2379x over previous
//
#include <hip/hip_runtime.h>
#include <math.h>

#define NHEAD 8
#define BATCH 4
#define NN 1024              // H*W
#define MM 21
#define DD 84                // M*hd
#define BN (BATCH*NHEAD)     // 32
#define NROWS (BATCH*NN*MM)  // 86016

typedef __attribute__((ext_vector_type(8))) short bf16x8;
typedef __attribute__((ext_vector_type(4))) float f32x4;
typedef __attribute__((ext_vector_type(16))) float f32x16;

__device__ __forceinline__ unsigned short f2bf(float x) {
    union { float f; unsigned int u; } c; c.f = x;
    unsigned int r = (c.u + 0x7FFFu + ((c.u >> 16) & 1u)) >> 16;
    return (unsigned short)r;
}

// ---------------- Kernel A: qkv projection -> bf16 q,k,v all [bh][n][84]; q pre-scaled 1/32 ----------------
__global__ __launch_bounds__(256)
void qkv_kernel(const float* __restrict__ x, const float* __restrict__ Wq,
                const float* __restrict__ bq, ushort* __restrict__ qb,
                ushort* __restrict__ kb, ushort* __restrict__ vb)
{
    __shared__ __align__(16) float xs[32*36];
    __shared__ __align__(16) float wq[32*96];
    __shared__ float bqs[96];
    int t = threadIdx.x;
    int R0 = blockIdx.x * 32;
    for (int i = t; i < 3072; i += 256) wq[i] = Wq[i];
    if (t < 96) bqs[t] = bq[t];
    const float* xb = x + (size_t)R0 * 32;
    for (int i = t; i < 1024; i += 256)
        xs[(i >> 5) * 36 + (i & 31)] = xb[i];
    __syncthreads();

    int row = t >> 3;
    int cj  = t & 7;           // owns cols cj*12 .. cj*12+11
    float acc[12];
#pragma unroll
    for (int cc = 0; cc < 12; cc++) acc[cc] = bqs[cj*12 + cc];
    const float4* xr = (const float4*)(xs + row*36);
#pragma unroll
    for (int k4 = 0; k4 < 8; k4++) {
        float4 xa = xr[k4];
        float xv[4] = {xa.x, xa.y, xa.z, xa.w};
#pragma unroll
        for (int u = 0; u < 4; u++) {
            int kk = k4*4 + u;
            const float4* wr = (const float4*)(wq + kk*96 + cj*12);
            float4 w0 = wr[0], w1 = wr[1], w2 = wr[2];
            acc[0] += xv[u]*w0.x; acc[1]  += xv[u]*w0.y; acc[2]  += xv[u]*w0.z; acc[3]  += xv[u]*w0.w;
            acc[4] += xv[u]*w1.x; acc[5]  += xv[u]*w1.y; acc[6]  += xv[u]*w1.z; acc[7]  += xv[u]*w1.w;
            acc[8] += xv[u]*w2.x; acc[9]  += xv[u]*w2.y; acc[10] += xv[u]*w2.z; acc[11] += xv[u]*w2.w;
        }
    }
    int R = R0 + row;
    int b_ = R / 21;
    int m  = R - b_*21;
    int b  = b_ >> 10;
    int n  = b_ & 1023;
#pragma unroll
    for (int g4 = 0; g4 < 3; g4++) {
        int c0 = cj*12 + g4*4;
        int s  = c0 >> 5;
        int hh = (c0 & 31) >> 2;
        float sc = (s == 0) ? 0.03125f : 1.0f;   // fold qk scale into q
        ushort4 pk;
        pk.x = f2bf(acc[g4*4+0]*sc); pk.y = f2bf(acc[g4*4+1]*sc);
        pk.z = f2bf(acc[g4*4+2]*sc); pk.w = f2bf(acc[g4*4+3]*sc);
        ushort* dst = (s == 0) ? qb : (s == 1) ? kb : vb;
        *(ushort4*)(dst + (((size_t)(b*NHEAD + hh))*NN + n)*DD + m*4) = pk;
    }
}

// ---------------- Kernel A2: transpose v [bh][n][84] -> vT [bh][84][n] ----------------
__global__ __launch_bounds__(256)
void vtr_kernel(const ushort* __restrict__ vb, ushort* __restrict__ vtb)
{
    __shared__ ushort ld[64*88];
    int t = threadIdx.x;
    int bh = blockIdx.y, n0 = blockIdx.x * 64;
    for (int i = t; i < 1344; i += 256) {
        int r = i/21, p = i - r*21;
        *(ushort4*)(ld + r*88 + p*4) = *(const ushort4*)(vb + ((size_t)bh*NN + n0 + r)*DD + p*4);
    }
    __syncthreads();
    for (int j = t; j < 1344; j += 256) {
        int d = j >> 4, g = j & 15;
        ushort4 wv;
        wv.x = ld[(g*4+0)*88 + d]; wv.y = ld[(g*4+1)*88 + d];
        wv.z = ld[(g*4+2)*88 + d]; wv.w = ld[(g*4+3)*88 + d];
        *(ushort4*)(vtb + ((size_t)bh*DD + d)*NN + n0 + g*4) = wv;
    }
}

// ---------------- Kernel B: x2[b,h,n] = x row . W_sq + b_sq  (+ init Mg) ----------------
__global__ __launch_bounds__(256)
void x2_kernel(const float* __restrict__ x, const float* __restrict__ Wsq,
               const float* __restrict__ bsq, float* __restrict__ x2,
               unsigned* __restrict__ Mg)
{
    __shared__ __align__(16) float ws[84];
    int t = threadIdx.x;
    if (t < 84) ws[t] = Wsq[t];
    if (blockIdx.x == 0 && t < 8) Mg[t] = 0u;
    __syncthreads();
    int i = blockIdx.x * 256 + t;
    int b = i >> 13;
    int h = (i >> 10) & 7;
    int n = i & 1023;
    const float* xr = x + ((size_t)(b*NN + n))*672 + h*4;
    float acc = bsq[0];
#pragma unroll
    for (int m = 0; m < 21; m++) {
        float4 xv = *(const float4*)(xr + m*32);
        float4 wv = *(const float4*)(ws + m*4);
        acc += xv.x*wv.x + xv.y*wv.y + xv.z*wv.z + xv.w*wv.w;
    }
    x2[i] = acc;
}

// ---------------- Kernel C: per-(b,h) avg+max pool ----------------
__global__ __launch_bounds__(256)
void pool_kernel(const float* __restrict__ x2, float* __restrict__ spool)
{
    int bh = blockIdx.x;
    int t = threadIdx.x;
    const float* p = x2 + (size_t)bh*NN;
    float s = 0.f, mx = -INFINITY;
    for (int i = t; i < NN; i += 256) { float v = p[i]; s += v; mx = fmaxf(mx, v); }
#pragma unroll
    for (int off = 1; off < 64; off <<= 1) {
        s  += __shfl_xor(s, off);
        mx  = fmaxf(mx, __shfl_xor(mx, off));
    }
    __shared__ float rs[4], rm[4];
    int w = t >> 6;
    if ((t & 63) == 0) { rs[w] = s; rm[w] = mx; }
    __syncthreads();
    if (t == 0) {
        float ss = rs[0]+rs[1]+rs[2]+rs[3];
        float mm = fmaxf(fmaxf(rm[0],rm[1]), fmaxf(rm[2],rm[3]));
        spool[bh] = ss * (1.f/1024.f) + mm;
    }
}

// ---------------- Kernel D: depthwise conv + pooled, batch-mean -> xw, xp ----------------
__global__ __launch_bounds__(256)
void lspe_kernel(const float* __restrict__ x2, const float* __restrict__ spool,
                 const float* __restrict__ Wdw, const float* __restrict__ bdw,
                 float* __restrict__ xw, float* __restrict__ xp)
{
    int i = blockIdx.x*256 + threadIdx.x;
    int h = i >> 10;
    int n = i & 1023;
    int y = n >> 5, xx = n & 31;
    int g0 = h >> 1;
    float accW = 0.f, accP = 0.f;
    for (int b = 0; b < 4; b++) {
        float sp = spool[b*8 + h];
        float c0 = bdw[h], c1 = bdw[8 + h];
        const float* a0 = x2 + (size_t)(b*8 + g0)*NN;
        const float* a1 = x2 + (size_t)(b*8 + 4 + g0)*NN;
#pragma unroll
        for (int ky = 0; ky < 3; ky++) {
            int yy = y + ky - 1;
            if (yy < 0 || yy > 31) continue;
#pragma unroll
            for (int kx = 0; kx < 3; kx++) {
                int xc = xx + kx - 1;
                if (xc < 0 || xc > 31) continue;
                c0 += a0[yy*32 + xc] * Wdw[h*9 + ky*3 + kx];
                c1 += a1[yy*32 + xc] * Wdw[(8+h)*9 + ky*3 + kx];
            }
        }
        accW += c0 + sp;
        accP += c1 + sp;
    }
    xw[i] = 0.25f * accW;
    xp[i] = 0.25f * accP;
}

// ---------------- Kernel E: correlation -> 63x63 bias table + per-head global max ----------------
__global__ __launch_bounds__(256)
void bias_kernel(const float* __restrict__ xw, const float* __restrict__ xp,
                 float* __restrict__ btab, unsigned* __restrict__ Mg)
{
    __shared__ float sxw[1024], sxp[1024];
    int h = blockIdx.y;
    int t = threadIdx.x;
    for (int i = t; i < 1024; i += 256) { sxw[i] = xw[h*1024+i]; sxp[i] = xp[h*1024+i]; }
    __syncthreads();
    int p = blockIdx.x*256 + t;
    int oy = p / 63, ox = p - oy*63;
    int alo = max(0, oy-31), ahi = min(31, oy);
    int clo = max(0, ox-31), chi = min(31, ox);
    float acc = 0.f;
    for (int a = alo; a <= ahi; a++)
        for (int c = clo; c <= chi; c++)
            acc += sxp[a*32 + c] * sxw[(oy-a)*32 + (ox-c)];
    unsigned key = 0u;
    if (p < 3969) {
        btab[h*3969 + p] = acc;
        unsigned u = __float_as_uint(acc);
        key = (u & 0x80000000u) ? ~u : (u | 0x80000000u);
    }
#pragma unroll
    for (int off = 1; off < 64; off <<= 1) {
        unsigned o = __shfl_xor(key, off);
        key = key > o ? key : o;
    }
    if ((t & 63) == 0) atomicMax(Mg + h, key);
}

// ---------------- Kernel F: MFMA flash attention, 32x32x16, no online softmax ----------------
// Block: 64 q-rows, 4 waves: wave (rh,kh) = rows rh*32+0..31, keys kh*32+0..31 of each 64-key tile.
#define SKB 104   // qs/ks row stride (ushort): 96 kdim + 8; /8 odd -> uniform banks
#define VST 72    // vt row stride: 64 keys + 8
#define PST 72    // ps row stride
__global__ __launch_bounds__(256, 2)
void attn_kernel(const ushort* __restrict__ qg, const ushort* __restrict__ kg,
                 const ushort* __restrict__ vg, const float* __restrict__ btg,
                 const unsigned* __restrict__ Mg, float* __restrict__ Obuf)
{
    __shared__ __align__(16) ushort smem[64*SKB + 64*SKB + 96*VST + 64*PST + 2*2079];
    ushort* qs = smem;
    ushort* ks = qs + 64*SKB;
    ushort* vt = ks + 64*SKB;
    ushort* ps = vt + 96*VST;
    float* btabS = (float*)(ps + 64*PST);   // 2079 floats: 33 table rows for this q-tile

    int t   = threadIdx.x;
    int bid = blockIdx.x;
    int qt  = bid & 15;
    int bh  = bid >> 4;
    int h   = bh & 7;
    int b   = bh >> 3;
    int q0  = qt * 64;

    float Mh;
    { unsigned k = Mg[h]; unsigned u = (k & 0x80000000u) ? (k ^ 0x80000000u) : ~k; Mh = __uint_as_float(u); }
    // bias slice (rows 2qt..2qt+32) minus global max
    const float* bsrc = btg + h*3969 + qt*126;
    for (int i = t; i < 2079; i += 256) btabS[i] = bsrc[i] - Mh;

    // zero kdim pads 84..95 for qs/ks; vt rows 85..95 zero, row 84 = ones (l accumulator)
    unsigned* qsu = (unsigned*)qs;
    unsigned* ksu = (unsigned*)ks;
    unsigned* vtu = (unsigned*)vt;
    for (int i = t; i < 384; i += 256) { int r = i/6, p = i%6; qsu[(r*SKB+84)/2 + p] = 0u; ksu[(r*SKB+84)/2 + p] = 0u; }
    for (int i = t; i < 396; i += 256) { int r = 85 + i/36, p = i%36; vtu[(r*VST)/2 + p] = 0u; }
    for (int i = t; i < 36; i += 256) vtu[(84*VST)/2 + i] = 0x3F803F80u;

    // stage Q (64 x 84)
    const ushort* qrow = qg + ((size_t)bh*NN + q0)*DD;
    for (int i = t; i < 1344; i += 256) {
        int r = i/21, p = i - r*21;
        *(ushort4*)(qs + r*SKB + p*4) = *(const ushort4*)(qrow + r*DD + p*4);
    }
    __syncthreads();

    int w    = t >> 6;
    int lane = t & 63;
    int rh   = w & 1;
    int kh   = w >> 1;
    int col  = lane & 31;
    int half = lane >> 5;
    int nlocal = rh*32 + col;          // local q-row (B n-index and PV A m-index)
    int nq   = q0 + nlocal;
    int rowbase = ((nlocal >> 5) + 31)*63 + (nq & 31) + 31;

    // loop-invariant Q B-frags
    bf16x8 bq[6];
#pragma unroll
    for (int s = 0; s < 6; s++)
        bq[s] = *(const bf16x8*)(qs + nlocal*SKB + s*16 + half*8);

    // key-offset registers: keyoff(nk) = nk + 31*(nk>>5); += 126 per 64-key tile
    int keyoff[16];
#pragma unroll
    for (int r = 0; r < 16; r++) {
        int kp = (r & 3) + 8*(r >> 2) + 4*half + kh*32;
        keyoff[r] = kp + (kp >> 5)*31;
    }

    f32x16 of[3];
#pragma unroll
    for (int f = 0; f < 3; f++)
#pragma unroll
        for (int r = 0; r < 16; r++) of[f][r] = 0.f;

    for (int kt = 0; kt < 16; kt++) {
        __syncthreads();
        const ushort* krow = kg + ((size_t)bh*NN + kt*64)*DD;
        const ushort* vrow = vg + (size_t)bh*DD*NN + kt*64;
        for (int i = t; i < 1344; i += 256) {
            int r = i/21, p = i - r*21;
            *(ushort4*)(ks + r*SKB + p*4) = *(const ushort4*)(krow + r*DD + p*4);
        }
        for (int i = t; i < 1344; i += 256) {
            int d = i >> 4, p = i & 15;
            *(ushort4*)(vt + d*VST + p*4) = *(const ushort4*)(vrow + (size_t)d*NN + p*4);
        }
        __syncthreads();

        // St = K . Q^T : A = K rows (this wave's key half), B = Q rows
        f32x16 st;
#pragma unroll
        for (int r = 0; r < 16; r++) st[r] = 0.f;
#pragma unroll
        for (int s = 0; s < 6; s++) {
            bf16x8 ak = *(const bf16x8*)(ks + (kh*32 + col)*SKB + s*16 + half*8);
            st = __builtin_amdgcn_mfma_f32_32x32x16_bf16(ak, bq[s], st, 0, 0, 0);
        }

        // P = exp(qk + bias - M); pack bf16 4-at-a-time into ps
#pragma unroll
        for (int g = 0; g < 4; g++) {
            float p0 = __expf(st[4*g+0] + btabS[rowbase - keyoff[4*g+0]]);
            float p1 = __expf(st[4*g+1] + btabS[rowbase - keyoff[4*g+1]]);
            float p2 = __expf(st[4*g+2] + btabS[rowbase - keyoff[4*g+2]]);
            float p3 = __expf(st[4*g+3] + btabS[rowbase - keyoff[4*g+3]]);
            ushort4 pk;
            pk.x = f2bf(p0); pk.y = f2bf(p1); pk.z = f2bf(p2); pk.w = f2bf(p3);
            *(ushort4*)(ps + nlocal*PST + kh*32 + g*8 + half*4) = pk;
        }
#pragma unroll
        for (int r = 0; r < 16; r++) keyoff[r] += 126;

        // O += P . V (A = ps rows, B = vt rows); l accumulates via ones-row d=84
        bf16x8 pa0 = *(const bf16x8*)(ps + nlocal*PST + kh*32 + half*8);
        bf16x8 pa1 = *(const bf16x8*)(ps + nlocal*PST + kh*32 + 16 + half*8);
#pragma unroll
        for (int f = 0; f < 3; f++) {
            bf16x8 b0 = *(const bf16x8*)(vt + (f*32 + col)*VST + kh*32 + half*8);
            bf16x8 b1 = *(const bf16x8*)(vt + (f*32 + col)*VST + kh*32 + 16 + half*8);
            of[f] = __builtin_amdgcn_mfma_f32_32x32x16_bf16(pa0, b0, of[f], 0, 0, 0);
            of[f] = __builtin_amdgcn_mfma_f32_32x32x16_bf16(pa1, b1, of[f], 0, 0, 0);
        }
    }

    // ---- cross-keyhalf reduce + epilogue ----
    __syncthreads();
    float* red = (float*)smem;          // overlay qs+ks: 128 lanes * 52 floats = 26624 B
    int lid = rh*64 + lane;
    if (kh == 1) {
        float4* dst = (float4*)(red + lid*52);
#pragma unroll
        for (int f = 0; f < 3; f++)
#pragma unroll
            for (int u = 0; u < 4; u++) {
                float4 v;
                v.x = of[f][u*4+0]; v.y = of[f][u*4+1]; v.z = of[f][u*4+2]; v.w = of[f][u*4+3];
                dst[f*4 + u] = v;
            }
    }
    __syncthreads();
    if (kh == 0) {
        const float4* src = (const float4*)(red + lid*52);
#pragma unroll
        for (int f = 0; f < 3; f++)
#pragma unroll
            for (int u = 0; u < 4; u++) {
                float4 v = src[f*4 + u];
                of[f][u*4+0] += v.x; of[f][u*4+1] += v.y; of[f][u*4+2] += v.z; of[f][u*4+3] += v.w;
            }
        float linv[16];
#pragma unroll
        for (int r = 0; r < 16; r++) {
            float lv = __shfl(of[2][r], (lane & 32) + 20);   // d=84 ones-row sum
            linv[r] = 1.f / lv;
        }
#pragma unroll
        for (int f = 0; f < 3; f++) {
            int d = f*32 + col;
            if (d < DD) {
                int m2 = d >> 2, c2 = h*4 + (d & 3);
#pragma unroll
                for (int r = 0; r < 16; r++) {
                    int rowl = rh*32 + (r & 3) + 8*(r >> 2) + 4*half;
                    int nq2 = q0 + rowl;
                    size_t R = ((size_t)(b*NN + nq2))*21 + m2;
                    Obuf[R*32 + c2] = of[f][r] * linv[r];
                }
            }
        }
    }
}

// ---------------- Kernel G: output projection (coalesced Obuf rows) ----------------
__global__ __launch_bounds__(256)
void proj_kernel(const float* __restrict__ Obuf, const float* __restrict__ Wp,
                 const float* __restrict__ bp, float* __restrict__ out)
{
    __shared__ __align__(16) float xs[32*36];
    __shared__ __align__(16) float wp[1024];
    __shared__ float bps[32];
    int t = threadIdx.x;
    int R0 = blockIdx.x * 32;
    for (int i = t; i < 1024; i += 256) wp[i] = Wp[i];
    if (t < 32) bps[t] = bp[t];
    for (int i = t; i < 1024; i += 256) {
        int row = i >> 5, c = i & 31;
        xs[row*36 + c] = Obuf[(size_t)R0*32 + i];
    }
    __syncthreads();
    int row = t >> 3, cj = t & 7;
    float acc[4];
#pragma unroll
    for (int cc = 0; cc < 4; cc++) acc[cc] = bps[cj*4 + cc];
    const float4* xr = (const float4*)(xs + row*36);
#pragma unroll
    for (int k4 = 0; k4 < 8; k4++) {
        float4 xa = xr[k4];
        float xv[4] = {xa.x, xa.y, xa.z, xa.w};
#pragma unroll
        for (int u = 0; u < 4; u++) {
            int kk = k4*4 + u;
            float4 w = *(const float4*)(wp + kk*32 + cj*4);
            acc[0] += xv[u]*w.x; acc[1] += xv[u]*w.y; acc[2] += xv[u]*w.z; acc[3] += xv[u]*w.w;
        }
    }
    *(float4*)(out + (size_t)(R0+row)*32 + cj*4) = make_float4(acc[0], acc[1], acc[2], acc[3]);
}

extern "C" void kernel_launch(void* const* d_in, const int* in_sizes, int n_in,
                              void* d_out, int out_size, void* d_ws, size_t ws_size,
                              hipStream_t stream)
{
    const float* x     = (const float*)d_in[0];
    const float* Wqkv  = (const float*)d_in[1];
    const float* bqkv  = (const float*)d_in[2];
    const float* Wproj = (const float*)d_in[3];
    const float* bproj = (const float*)d_in[4];
    const float* Wsq   = (const float*)d_in[5];
    const float* bsq   = (const float*)d_in[6];
    const float* Wdw   = (const float*)d_in[7];
    const float* bdw   = (const float*)d_in[8];

    const size_t QKV = (size_t)BN * NN * DD;    // 2,752,512
    ushort* qb   = (ushort*)d_ws;
    ushort* kb   = qb + QKV;
    ushort* vb   = kb + QKV;
    ushort* vtb  = vb + QKV;
    float* Obuf  = (float*)(vtb + QKV);
    float* x2    = Obuf + QKV;
    float* spool = x2 + 32768;
    float* xw    = spool + 32;
    float* xp    = xw + 8192;
    float* btab  = xp + 8192;
    unsigned* Mg = (unsigned*)(btab + 3969*8);
    float* out   = (float*)d_out;

    qkv_kernel <<<NROWS/32,   256, 0, stream>>>(x, Wqkv, bqkv, qb, kb, vb);
    vtr_kernel <<<dim3(16,32),256, 0, stream>>>(vb, vtb);
    x2_kernel  <<<128,        256, 0, stream>>>(x, Wsq, bsq, x2, Mg);
    pool_kernel<<<32,         256, 0, stream>>>(x2, spool);
    lspe_kernel<<<32,         256, 0, stream>>>(x2, spool, Wdw, bdw, xw, xp);
    bias_kernel<<<dim3(16,8), 256, 0, stream>>>(xw, xp, btab, Mg);
    attn_kernel<<<512,        256, 0, stream>>>(qb, kb, vtb, btab, Mg, Obuf);
    proj_kernel<<<NROWS/32,   256, 0, stream>>>(Obuf, Wproj, bproj, out);
}

// Round 4
// 206.136 us; speedup vs baseline: 2.5301x; 1.2436x over previous
//
#include <hip/hip_runtime.h>
#include <math.h>

#define NHEAD 8
#define BATCH 4
#define NN 1024              // H*W
#define MM 21
#define DD 84                // M*hd
#define DP 96                // padded feature dim
#define BN (BATCH*NHEAD)     // 32
#define NROWS (BATCH*NN*MM)  // 86016

typedef __attribute__((ext_vector_type(8))) short bf16x8;
typedef __attribute__((ext_vector_type(16))) float f32x16;

__device__ __forceinline__ unsigned short f2bf(float x) {
    union { float f; unsigned int u; } c; c.f = x;
    unsigned int r = (c.u + 0x7FFFu + ((c.u >> 16) & 1u)) >> 16;
    return (unsigned short)r;
}
__device__ __forceinline__ int qxmap(int r, int half) { return (r & 3) + 8*(r >> 2) + 4*half; }

// ---------------- Kernel A: qkv projection via MFMA -> q,k [bh][n][96] (q pre-scaled), v [bh][n][84] ----------------
__global__ __launch_bounds__(256)
void qkv_kernel(const float* __restrict__ x, const float* __restrict__ Wq,
                const float* __restrict__ bq, ushort* __restrict__ qb,
                ushort* __restrict__ kb, ushort* __restrict__ vb)
{
    __shared__ ushort wqs[3072];
    __shared__ float bqs[96];
    __shared__ ushort cs[4*3200];      // per-wave 32x(96+4) repack
    int t = threadIdx.x;
    int w = t >> 6, lane = t & 63, col = lane & 31, half = lane >> 5;
    int R0 = blockIdx.x * 128;

    for (int i = t; i < 3072; i += 256) wqs[i] = f2bf(Wq[i]);
    if (t < 96) bqs[t] = bq[t];
    __syncthreads();

    // B-frags: B[k][n], k = c*16 + half*8 + j, n = f*32+col
    bf16x8 bw[3][2];
#pragma unroll
    for (int f = 0; f < 3; f++)
#pragma unroll
        for (int c = 0; c < 2; c++) {
            union { bf16x8 v; ushort s[8]; } u;
#pragma unroll
            for (int j = 0; j < 8; j++)
                u.s[j] = wqs[(c*16 + half*8 + j)*96 + f*32 + col];
            bw[f][c] = u.v;
        }
    // A-frags: x row R, k-cols
    int R = R0 + w*32 + col;
    bf16x8 aw[2];
#pragma unroll
    for (int c = 0; c < 2; c++) {
        float4 v0 = *(const float4*)(x + (size_t)R*32 + c*16 + half*8);
        float4 v1 = *(const float4*)(x + (size_t)R*32 + c*16 + half*8 + 4);
        union { bf16x8 v; ushort s[8]; } u;
        u.s[0]=f2bf(v0.x); u.s[1]=f2bf(v0.y); u.s[2]=f2bf(v0.z); u.s[3]=f2bf(v0.w);
        u.s[4]=f2bf(v1.x); u.s[5]=f2bf(v1.y); u.s[6]=f2bf(v1.z); u.s[7]=f2bf(v1.w);
        aw[c] = u.v;
    }
    f32x16 acc[3];
#pragma unroll
    for (int f = 0; f < 3; f++) {
#pragma unroll
        for (int r = 0; r < 16; r++) acc[f][r] = 0.f;
#pragma unroll
        for (int c = 0; c < 2; c++)
            acc[f] = __builtin_amdgcn_mfma_f32_32x32x16_bf16(aw[c], bw[f][c], acc[f], 0, 0, 0);
    }
    // repack through per-wave LDS
    ushort* myc = cs + w*3200;
#pragma unroll
    for (int f = 0; f < 3; f++) {
        float sc = (f == 0) ? 0.03125f : 1.0f;   // fold qk scale into q
        float bb = bqs[f*32 + col];
#pragma unroll
        for (int r = 0; r < 16; r++)
            myc[qxmap(r, half)*100 + f*32 + col] = f2bf((acc[f][r] + bb)*sc);
    }
    __syncthreads();
    int row = lane >> 1, hr = lane & 1;
    int Rr = R0 + w*32 + row;
    int b_ = Rr / 21, m = Rr - b_*21, b = b_ >> 10, n = b_ & 1023;
#pragma unroll
    for (int c2 = 0; c2 < 12; c2++) {
        int col4 = hr*48 + c2*4;
        ushort4 v = *(const ushort4*)(myc + row*100 + col4);
        int s = col4 >> 5, hh = (col4 & 31) >> 2;
        size_t bhn = (size_t)((b*8 + hh)*1024 + n);
        if (s == 0)      *(ushort4*)(qb + bhn*DP + m*4) = v;
        else if (s == 1) *(ushort4*)(kb + bhn*DP + m*4) = v;
        else             *(ushort4*)(vb + bhn*DD + m*4) = v;
    }
}

// ---------------- Kernel A2: v [bh][n][84] -> vT [bh][96][1024] (row 84 = ones, 85..95 = 0) ----------------
__global__ __launch_bounds__(256)
void vtr_kernel(const ushort* __restrict__ vb, ushort* __restrict__ vtb)
{
    __shared__ ushort ld[64*88];
    int t = threadIdx.x;
    int bh = blockIdx.y, n0 = blockIdx.x * 64;
    for (int i = t; i < 1344; i += 256) {
        int r = i/21, p = i - r*21;
        *(ushort4*)(ld + r*88 + p*4) = *(const ushort4*)(vb + ((size_t)bh*NN + n0 + r)*DD + p*4);
    }
    __syncthreads();
    for (int j = t; j < 1344; j += 256) {
        int d = j >> 4, g = j & 15;
        ushort4 wv;
        wv.x = ld[(g*4+0)*88 + d]; wv.y = ld[(g*4+1)*88 + d];
        wv.z = ld[(g*4+2)*88 + d]; wv.w = ld[(g*4+3)*88 + d];
        *(ushort4*)(vtb + ((size_t)bh*DP + d)*NN + n0 + g*4) = wv;
    }
    if (t < 192) {
        int r = 84 + t/16, p = t & 15;
        ushort e = (r == 84) ? (ushort)0x3F80 : (ushort)0;
        ushort4 v = make_ushort4(e, e, e, e);
        *(ushort4*)(vtb + ((size_t)bh*DP + r)*NN + n0 + p*4) = v;
    }
}

// ---------------- Kernel B: x2 = x . W_sq + b_sq ; init Mg ; zero q/k pads ----------------
__global__ __launch_bounds__(256)
void x2_kernel(const float* __restrict__ x, const float* __restrict__ Wsq,
               const float* __restrict__ bsq, float* __restrict__ x2,
               unsigned* __restrict__ Mg, ushort* __restrict__ qb,
               ushort* __restrict__ kb)
{
    __shared__ __align__(16) float ws[84];
    int t = threadIdx.x;
    if (t < 84) ws[t] = Wsq[t];
    if (blockIdx.x == 0 && t < 8) Mg[t] = 0u;
    __syncthreads();
    int i = blockIdx.x * 256 + t;        // (b*8+h)*1024 + n
    int b = i >> 13;
    int h = (i >> 10) & 7;
    int n = i & 1023;
    const float* xr = x + ((size_t)(b*NN + n))*672 + h*4;
    float acc = bsq[0];
#pragma unroll
    for (int m = 0; m < 21; m++) {
        float4 xv = *(const float4*)(xr + m*32);
        float4 wv = *(const float4*)(ws + m*4);
        acc += xv.x*wv.x + xv.y*wv.y + xv.z*wv.z + xv.w*wv.w;
    }
    x2[i] = acc;
    // zero d=84..95 pads of q,k for row i
    ushort4 z = make_ushort4(0,0,0,0);
    size_t pb = (size_t)i*DP + 84;
    *(ushort4*)(qb + pb) = z; *(ushort4*)(qb + pb + 4) = z; *(ushort4*)(qb + pb + 8) = z;
    *(ushort4*)(kb + pb) = z; *(ushort4*)(kb + pb + 4) = z; *(ushort4*)(kb + pb + 8) = z;
}

// ---------------- Kernel C: per-(b,h) avg+max pool ----------------
__global__ __launch_bounds__(256)
void pool_kernel(const float* __restrict__ x2, float* __restrict__ spool)
{
    int bh = blockIdx.x;
    int t = threadIdx.x;
    const float* p = x2 + (size_t)bh*NN;
    float s = 0.f, mx = -INFINITY;
    for (int i = t; i < NN; i += 256) { float v = p[i]; s += v; mx = fmaxf(mx, v); }
#pragma unroll
    for (int off = 1; off < 64; off <<= 1) {
        s  += __shfl_xor(s, off);
        mx  = fmaxf(mx, __shfl_xor(mx, off));
    }
    __shared__ float rs[4], rm[4];
    int w = t >> 6;
    if ((t & 63) == 0) { rs[w] = s; rm[w] = mx; }
    __syncthreads();
    if (t == 0) {
        float ss = rs[0]+rs[1]+rs[2]+rs[3];
        float mm = fmaxf(fmaxf(rm[0],rm[1]), fmaxf(rm[2],rm[3]));
        spool[bh] = ss * (1.f/1024.f) + mm;
    }
}

// ---------------- Kernel D: depthwise conv + pooled, batch-mean -> xw, xp ----------------
__global__ __launch_bounds__(256)
void lspe_kernel(const float* __restrict__ x2, const float* __restrict__ spool,
                 const float* __restrict__ Wdw, const float* __restrict__ bdw,
                 float* __restrict__ xw, float* __restrict__ xp)
{
    int i = blockIdx.x*256 + threadIdx.x;
    int h = i >> 10;
    int n = i & 1023;
    int y = n >> 5, xx = n & 31;
    int g0 = h >> 1;
    float accW = 0.f, accP = 0.f;
    for (int b = 0; b < 4; b++) {
        float sp = spool[b*8 + h];
        float c0 = bdw[h], c1 = bdw[8 + h];
        const float* a0 = x2 + (size_t)(b*8 + g0)*NN;
        const float* a1 = x2 + (size_t)(b*8 + 4 + g0)*NN;
#pragma unroll
        for (int ky = 0; ky < 3; ky++) {
            int yy = y + ky - 1;
            if (yy < 0 || yy > 31) continue;
#pragma unroll
            for (int kx = 0; kx < 3; kx++) {
                int xc = xx + kx - 1;
                if (xc < 0 || xc > 31) continue;
                c0 += a0[yy*32 + xc] * Wdw[h*9 + ky*3 + kx];
                c1 += a1[yy*32 + xc] * Wdw[(8+h)*9 + ky*3 + kx];
            }
        }
        accW += c0 + sp;
        accP += c1 + sp;
    }
    xw[i] = 0.25f * accW;
    xp[i] = 0.25f * accP;
}

// ---------------- Kernel E: correlation -> 63x63 bias table + per-head global max ----------------
__global__ __launch_bounds__(256)
void bias_kernel(const float* __restrict__ xw, const float* __restrict__ xp,
                 float* __restrict__ btab, unsigned* __restrict__ Mg)
{
    __shared__ float sxw[1024], sxp[1024];
    int h = blockIdx.y;
    int t = threadIdx.x;
    for (int i = t; i < 1024; i += 256) { sxw[i] = xw[h*1024+i]; sxp[i] = xp[h*1024+i]; }
    __syncthreads();
    int p = blockIdx.x*256 + t;
    int oy = p / 63, ox = p - oy*63;
    int alo = max(0, oy-31), ahi = min(31, oy);
    int clo = max(0, ox-31), chi = min(31, ox);
    float acc = 0.f;
    for (int a = alo; a <= ahi; a++)
        for (int c = clo; c <= chi; c++)
            acc += sxp[a*32 + c] * sxw[(oy-a)*32 + (ox-c)];
    unsigned key = 0u;
    if (p < 3969) {
        btab[h*3969 + p] = acc;
        unsigned u = __float_as_uint(acc);
        key = (u & 0x80000000u) ? ~u : (u | 0x80000000u);
    }
#pragma unroll
    for (int off = 1; off < 64; off <<= 1) {
        unsigned o = __shfl_xor(key, off);
        key = key > o ? key : o;
    }
    if ((t & 63) == 0) atomicMax(Mg + h, key);
}

// ---------------- Kernel F: barrier-free MFMA flash attention, direct-global fragments ----------------
// grid 1024: bid = bh*32 + qt; block = 4 independent waves; wave w owns key-tiles kt = 4j+w (32 keys = one y-row).
__global__ __launch_bounds__(256, 2)
void attn_kernel(const ushort* __restrict__ qg, const ushort* __restrict__ kg,
                 const ushort* __restrict__ vg, const float* __restrict__ btg,
                 const unsigned* __restrict__ Mg, float* __restrict__ Obuf)
{
    __shared__ float btabS[2016];        // 32 table rows for this q y-row
    __shared__ float red[2][64*52];
    __shared__ float lred[32];

    int t = threadIdx.x;
    int bid = blockIdx.x;
    int qt = bid & 31, bh = bid >> 5;
    int h = bh & 7, b = bh >> 3;
    int q0 = qt * 32;

    float Mh;
    { unsigned k = Mg[h]; unsigned u = (k & 0x80000000u) ? (k ^ 0x80000000u) : ~k; Mh = __uint_as_float(u); }
    const float* bsrc = btg + h*3969 + qt*63;      // rows yq .. yq+31
    for (int i = t; i < 2016; i += 256) btabS[i] = bsrc[i] - Mh;
    __syncthreads();

    int w = t >> 6, lane = t & 63, col = lane & 31, half = lane >> 5;

    // loop-invariant Q B-frags (B[k=d][n=q])
    bf16x8 bq6[6];
    const ushort* qrow = qg + ((size_t)(bh*NN) + q0 + col)*DP;
#pragma unroll
    for (int s = 0; s < 6; s++) bq6[s] = *(const bf16x8*)(qrow + s*16 + half*8);

    f32x16 of[3];
#pragma unroll
    for (int f = 0; f < 3; f++)
#pragma unroll
        for (int r = 0; r < 16; r++) of[f][r] = 0.f;

    int kx_[16];
#pragma unroll
    for (int r = 0; r < 16; r++) kx_[r] = qxmap(r, half);

    const ushort* kbase = kg + (size_t)bh*NN*DP;
    const ushort* vbase = vg + (size_t)bh*DP*NN;

    bf16x8 akc[6];
    {
        const ushort* kr = kbase + ((size_t)(w*32 + col))*DP;
#pragma unroll
        for (int s = 0; s < 6; s++) akc[s] = *(const bf16x8*)(kr + s*16 + half*8);
    }

    for (int j = 0; j < 8; j++) {
        int kt = 4*j + w;
        // V B-frags (B[k=key][n=d]) — issued early, consumed after softmax
        bf16x8 vf[3][2];
#pragma unroll
        for (int f = 0; f < 3; f++)
#pragma unroll
            for (int c = 0; c < 2; c++)
                vf[f][c] = *(const bf16x8*)(vbase + ((size_t)(f*32 + col))*NN + kt*32 + c*16 + half*8);

        // St = K.Q^T : D[m=key][n=q]
        f32x16 st;
#pragma unroll
        for (int r = 0; r < 16; r++) st[r] = 0.f;
#pragma unroll
        for (int s = 0; s < 6; s++)
            st = __builtin_amdgcn_mfma_f32_32x32x16_bf16(akc[s], bq6[s], st, 0, 0, 0);

        // prefetch next K tile
        bf16x8 akn[6];
        if (j < 7) {
            const ushort* kr = kbase + ((size_t)((kt+4)*32 + col))*DP;
#pragma unroll
            for (int s = 0; s < 6; s++) akn[s] = *(const bf16x8*)(kr + s*16 + half*8);
        }

        // P = exp(st + bias - M), packed to bf16 pairs (round-half-up)
        const float* bp = btabS + (31 - kt)*63 + col + 31;
        unsigned P[8];
#pragma unroll
        for (int g = 0; g < 8; g++) {
            float p0 = __expf(st[2*g]   + bp[-kx_[2*g]]);
            float p1 = __expf(st[2*g+1] + bp[-kx_[2*g+1]]);
            unsigned u0 = __float_as_uint(p0) + 0x8000u;
            unsigned u1 = __float_as_uint(p1) + 0x8000u;
            P[g] = (u1 & 0xFFFF0000u) | (u0 >> 16);
        }
        unsigned XP[8];
#pragma unroll
        for (int g = 0; g < 8; g++) XP[g] = (unsigned)__shfl_xor((int)P[g], 32);

        union { bf16x8 v; unsigned u[4]; } f0, f1;
        f0.u[0] = half ? XP[2] : P[0];
        f0.u[1] = half ? XP[3] : P[1];
        f0.u[2] = half ? P[2]  : XP[0];
        f0.u[3] = half ? P[3]  : XP[1];
        f1.u[0] = half ? XP[6] : P[4];
        f1.u[1] = half ? XP[7] : P[5];
        f1.u[2] = half ? P[6]  : XP[4];
        f1.u[3] = half ? P[7]  : XP[5];

        // O += P.V  : D[m=q][n=d] ; l accumulates via ones-row d=84
#pragma unroll
        for (int f = 0; f < 3; f++) {
            of[f] = __builtin_amdgcn_mfma_f32_32x32x16_bf16(f0.v, vf[f][0], of[f], 0, 0, 0);
            of[f] = __builtin_amdgcn_mfma_f32_32x32x16_bf16(f1.v, vf[f][1], of[f], 0, 0, 0);
        }
        if (j < 7) {
#pragma unroll
            for (int s = 0; s < 6; s++) akc[s] = akn[s];
        }
    }

    // ---- 4-way O reduction (tree) + epilogue ----
    __syncthreads();
    if (w == 1 || w == 3) {
        float* dst = red[w >> 1] + lane*52;
#pragma unroll
        for (int f = 0; f < 3; f++)
#pragma unroll
            for (int r = 0; r < 16; r++) dst[f*16 + r] = of[f][r];
    }
    __syncthreads();
    if (w == 0 || w == 2) {
        const float* src = red[w >> 1] + lane*52;
#pragma unroll
        for (int f = 0; f < 3; f++)
#pragma unroll
            for (int r = 0; r < 16; r++) of[f][r] += src[f*16 + r];
    }
    __syncthreads();
    if (w == 2) {
        float* dst = red[0] + lane*52;
#pragma unroll
        for (int f = 0; f < 3; f++)
#pragma unroll
            for (int r = 0; r < 16; r++) dst[f*16 + r] = of[f][r];
    }
    __syncthreads();
    if (w == 0) {
        const float* src = red[0] + lane*52;
#pragma unroll
        for (int f = 0; f < 3; f++)
#pragma unroll
            for (int r = 0; r < 16; r++) of[f][r] += src[f*16 + r];
        if (col == 20) {
#pragma unroll
            for (int r = 0; r < 16; r++) lred[qxmap(r, half)] = of[2][r];
        }
    }
    __syncthreads();
    if (w == 0) {
        float linv[16];
#pragma unroll
        for (int r = 0; r < 16; r++) linv[r] = 1.0f / lred[qxmap(r, half)];
#pragma unroll
        for (int f = 0; f < 3; f++) {
            int d = f*32 + col;
            if (d < DD) {
                int m = d >> 2, dd2 = d & 3;
#pragma unroll
                for (int r = 0; r < 16; r++) {
                    int q = qxmap(r, half);
                    size_t R = ((size_t)(b*NN + q0 + q))*21 + m;
                    Obuf[R*32 + h*4 + dd2] = of[f][r] * linv[r];
                }
            }
        }
    }
}

// ---------------- Kernel G: output projection via MFMA ----------------
__global__ __launch_bounds__(256)
void proj_kernel(const float* __restrict__ Obuf, const float* __restrict__ Wp,
                 const float* __restrict__ bp, float* __restrict__ out)
{
    __shared__ ushort wps[1024];
    __shared__ float bps[32];
    int t = threadIdx.x;
    int w = t >> 6, lane = t & 63, col = lane & 31, half = lane >> 5;
    int R0 = blockIdx.x * 128;
    for (int i = t; i < 1024; i += 256) wps[i] = f2bf(Wp[i]);
    if (t < 32) bps[t] = bp[t];
    __syncthreads();

    bf16x8 bw[2];
#pragma unroll
    for (int c = 0; c < 2; c++) {
        union { bf16x8 v; ushort s[8]; } u;
#pragma unroll
        for (int j = 0; j < 8; j++)
            u.s[j] = wps[(c*16 + half*8 + j)*32 + col];
        bw[c] = u.v;
    }
    int R = R0 + w*32 + col;
    bf16x8 aw[2];
#pragma unroll
    for (int c = 0; c < 2; c++) {
        float4 v0 = *(const float4*)(Obuf + (size_t)R*32 + c*16 + half*8);
        float4 v1 = *(const float4*)(Obuf + (size_t)R*32 + c*16 + half*8 + 4);
        union { bf16x8 v; ushort s[8]; } u;
        u.s[0]=f2bf(v0.x); u.s[1]=f2bf(v0.y); u.s[2]=f2bf(v0.z); u.s[3]=f2bf(v0.w);
        u.s[4]=f2bf(v1.x); u.s[5]=f2bf(v1.y); u.s[6]=f2bf(v1.z); u.s[7]=f2bf(v1.w);
        aw[c] = u.v;
    }
    f32x16 acc;
#pragma unroll
    for (int r = 0; r < 16; r++) acc[r] = 0.f;
#pragma unroll
    for (int c = 0; c < 2; c++)
        acc = __builtin_amdgcn_mfma_f32_32x32x16_bf16(aw[c], bw[c], acc, 0, 0, 0);
    float bb = bps[col];
#pragma unroll
    for (int r = 0; r < 16; r++)
        out[(size_t)(R0 + w*32 + qxmap(r, half))*32 + col] = acc[r] + bb;
}

extern "C" void kernel_launch(void* const* d_in, const int* in_sizes, int n_in,
                              void* d_out, int out_size, void* d_ws, size_t ws_size,
                              hipStream_t stream)
{
    const float* x     = (const float*)d_in[0];
    const float* Wqkv  = (const float*)d_in[1];
    const float* bqkv  = (const float*)d_in[2];
    const float* Wproj = (const float*)d_in[3];
    const float* bproj = (const float*)d_in[4];
    const float* Wsq   = (const float*)d_in[5];
    const float* bsq   = (const float*)d_in[6];
    const float* Wdw   = (const float*)d_in[7];
    const float* bdw   = (const float*)d_in[8];

    const size_t QP = (size_t)BN * NN * DP;   // 3,145,728
    const size_t VB = (size_t)BN * NN * DD;   // 2,752,512
    ushort* qb   = (ushort*)d_ws;
    ushort* kb   = qb + QP;
    ushort* vb   = kb + QP;
    ushort* vtb  = vb + VB;
    float* Obuf  = (float*)(vtb + QP);
    float* x2    = Obuf + VB;
    float* spool = x2 + 32768;
    float* xw    = spool + 32;
    float* xp    = xw + 8192;
    float* btab  = xp + 8192;
    unsigned* Mg = (unsigned*)(btab + 3969*8);
    float* out   = (float*)d_out;

    qkv_kernel <<<NROWS/128, 256, 0, stream>>>(x, Wqkv, bqkv, qb, kb, vb);
    vtr_kernel <<<dim3(16,32),256, 0, stream>>>(vb, vtb);
    x2_kernel  <<<128,        256, 0, stream>>>(x, Wsq, bsq, x2, Mg, qb, kb);
    pool_kernel<<<32,         256, 0, stream>>>(x2, spool);
    lspe_kernel<<<32,         256, 0, stream>>>(x2, spool, Wdw, bdw, xw, xp);
    bias_kernel<<<dim3(16,8), 256, 0, stream>>>(xw, xp, btab, Mg);
    attn_kernel<<<1024,       256, 0, stream>>>(qb, kb, vtb, btab, Mg, Obuf);
    proj_kernel<<<NROWS/128,  256, 0, stream>>>(Obuf, Wproj, bproj, out);
}

// Round 5
// 194.432 us; speedup vs baseline: 2.6824x; 1.0602x over previous
//
#include <hip/hip_runtime.h>
#include <math.h>

#define NHEAD 8
#define BATCH 4
#define NN 1024              // H*W
#define MM 21
#define DD 84                // M*hd
#define DP 96                // padded feature dim
#define BN (BATCH*NHEAD)     // 32
#define NROWS (BATCH*NN*MM)  // 86016

typedef __attribute__((ext_vector_type(8))) short bf16x8;
typedef __attribute__((ext_vector_type(16))) float f32x16;

__device__ __forceinline__ unsigned short f2bf(float x) {
    union { float f; unsigned int u; } c; c.f = x;
    unsigned int r = (c.u + 0x7FFFu + ((c.u >> 16) & 1u)) >> 16;
    return (unsigned short)r;
}
__device__ __forceinline__ int qxmap(int r, int half) { return (r & 3) + 8*(r >> 2) + 4*half; }

// Fragment-linear layouts (ushort):
//  Qf/Kf: addr(bh,n,d) = ((bh*32 + n/32)*6 + d/16)*512 + ((d>>3)&1)*256 + (n&31)*8 + (d&7)
//         i.e. tile base (bh*32+nt)*3072, frag (s,half) at s*512+half*256, lane col*8.
//  Vf:    addr(bh,n,d) = (bh*32 + n/32)*3072 + (d/32)*1024 + ((n>>4)&1)*512 + ((n>>3)&1)*256 + (d&31)*8 + (n&7)

// ---------------- Kernel A: qkv projection via MFMA -> Qf,Kf frag-layout (q pre-scaled), v row-major [bh][n][84] ----------------
__global__ __launch_bounds__(256)
void qkv_kernel(const float* __restrict__ x, const float* __restrict__ Wq,
                const float* __restrict__ bq, ushort* __restrict__ qf,
                ushort* __restrict__ kf, ushort* __restrict__ vb)
{
    __shared__ ushort wqs[3072];
    __shared__ float bqs[96];
    __shared__ __align__(16) float xs[128*36];
    __shared__ ushort cs[4*3200];      // per-wave 32x(96+4) repack
    int t = threadIdx.x;
    int w = t >> 6, lane = t & 63, col = lane & 31, half = lane >> 5;
    int R0 = blockIdx.x * 128;

    for (int i = t; i < 3072; i += 256) wqs[i] = f2bf(Wq[i]);
    if (t < 96) bqs[t] = bq[t];
    for (int i = t; i < 4096; i += 256)
        xs[(i >> 5)*36 + (i & 31)] = x[(size_t)R0*32 + i];
    __syncthreads();

    // B-frags: B[k][n], k = c*16 + half*8 + j, n = f*32+col
    bf16x8 bw[3][2];
#pragma unroll
    for (int f = 0; f < 3; f++)
#pragma unroll
        for (int c = 0; c < 2; c++) {
            union { bf16x8 v; ushort s[8]; } u;
#pragma unroll
            for (int j = 0; j < 8; j++)
                u.s[j] = wqs[(c*16 + half*8 + j)*96 + f*32 + col];
            bw[f][c] = u.v;
        }
    // A-frags from LDS-staged x
    bf16x8 aw[2];
#pragma unroll
    for (int c = 0; c < 2; c++) {
        const float* xr = xs + (w*32 + col)*36 + c*16 + half*8;
        float4 v0 = *(const float4*)(xr);
        float4 v1 = *(const float4*)(xr + 4);
        union { bf16x8 v; ushort s[8]; } u;
        u.s[0]=f2bf(v0.x); u.s[1]=f2bf(v0.y); u.s[2]=f2bf(v0.z); u.s[3]=f2bf(v0.w);
        u.s[4]=f2bf(v1.x); u.s[5]=f2bf(v1.y); u.s[6]=f2bf(v1.z); u.s[7]=f2bf(v1.w);
        aw[c] = u.v;
    }
    f32x16 acc[3];
#pragma unroll
    for (int f = 0; f < 3; f++) {
#pragma unroll
        for (int r = 0; r < 16; r++) acc[f][r] = 0.f;
#pragma unroll
        for (int c = 0; c < 2; c++)
            acc[f] = __builtin_amdgcn_mfma_f32_32x32x16_bf16(aw[c], bw[f][c], acc[f], 0, 0, 0);
    }
    // repack through per-wave LDS
    ushort* myc = cs + w*3200;
#pragma unroll
    for (int f = 0; f < 3; f++) {
        float sc = (f == 0) ? 0.03125f : 1.0f;   // fold qk scale into q
        float bb = bqs[f*32 + col];
#pragma unroll
        for (int r = 0; r < 16; r++)
            myc[qxmap(r, half)*100 + f*32 + col] = f2bf((acc[f][r] + bb)*sc);
    }
    __syncthreads();
    int row = lane >> 1, hr = lane & 1;
    int Rr = R0 + w*32 + row;
    int b_ = Rr / 21, m = Rr - b_*21, b = b_ >> 10, n = b_ & 1023;
    size_t fragoff = (size_t)(m >> 2)*512 + ((m >> 1) & 1)*256 + (n & 31)*8 + ((4*m) & 7);
    int nt = n >> 5;
#pragma unroll
    for (int c2 = 0; c2 < 12; c2++) {
        int col4 = hr*48 + c2*4;
        ushort4 v = *(const ushort4*)(myc + row*100 + col4);
        int s = col4 >> 5, hh = (col4 & 31) >> 2;
        if (s == 0)
            *(ushort4*)(qf + (size_t)((b*8 + hh)*32 + nt)*3072 + fragoff) = v;
        else if (s == 1)
            *(ushort4*)(kf + (size_t)((b*8 + hh)*32 + nt)*3072 + fragoff) = v;
        else
            *(ushort4*)(vb + ((size_t)((b*8 + hh)*1024 + n))*DD + m*4) = v;
    }
}

// ---------------- Kernel A2: v [bh][n][84] -> Vf frag layout (d=84 ones, 85..95 zero) ----------------
__global__ __launch_bounds__(256)
void vtr_kernel(const ushort* __restrict__ vb, ushort* __restrict__ vf)
{
    __shared__ ushort ld[64*88];
    int t = threadIdx.x;
    int bh = blockIdx.y, n0 = blockIdx.x * 64;
    for (int i = t; i < 1344; i += 256) {
        int r = i/21, p = i - r*21;
        *(ushort4*)(ld + r*88 + p*4) = *(const ushort4*)(vb + ((size_t)bh*NN + n0 + r)*DD + p*4);
    }
    __syncthreads();
    for (int j = t; j < 1344; j += 256) {
        int d = j >> 4, g = j & 15;
        ushort4 wv;
        wv.x = ld[(g*4+0)*88 + d]; wv.y = ld[(g*4+1)*88 + d];
        wv.z = ld[(g*4+2)*88 + d]; wv.w = ld[(g*4+3)*88 + d];
        int nn = n0 + g*4;
        size_t addr = (size_t)(bh*32 + (nn >> 5))*3072 + (d >> 5)*1024
                    + ((nn >> 4) & 1)*512 + ((nn >> 3) & 1)*256 + (d & 31)*8 + (nn & 7);
        *(ushort4*)(vf + addr) = wv;
    }
    if (t < 192) {
        int r = 84 + t/16, p = t & 15;
        int nn = n0 + p*4;
        ushort e = (r == 84) ? (ushort)0x3F80 : (ushort)0;
        size_t addr = (size_t)(bh*32 + (nn >> 5))*3072 + 2*1024
                    + ((nn >> 4) & 1)*512 + ((nn >> 3) & 1)*256 + (r & 31)*8 + (nn & 7);
        *(ushort4*)(vf + addr) = make_ushort4(e, e, e, e);
    }
}

// ---------------- Kernel B: x2 = x . W_sq + b_sq ; init Mg ; zero q/k frag pads (d=84..95) ----------------
__global__ __launch_bounds__(256)
void x2_kernel(const float* __restrict__ x, const float* __restrict__ Wsq,
               const float* __restrict__ bsq, float* __restrict__ x2,
               unsigned* __restrict__ Mg, ushort* __restrict__ qf,
               ushort* __restrict__ kf)
{
    __shared__ __align__(16) float ws[84];
    int t = threadIdx.x;
    if (t < 84) ws[t] = Wsq[t];
    if (blockIdx.x == 0 && t < 8) Mg[t] = 0u;
    __syncthreads();
    int i = blockIdx.x * 256 + t;        // (b*8+h)*1024 + n
    int b = i >> 13;
    int h = (i >> 10) & 7;
    int n = i & 1023;
    const float* xr = x + ((size_t)(b*NN + n))*672 + h*4;
    float acc = bsq[0];
#pragma unroll
    for (int m = 0; m < 21; m++) {
        float4 xv = *(const float4*)(xr + m*32);
        float4 wv = *(const float4*)(ws + m*4);
        acc += xv.x*wv.x + xv.y*wv.y + xv.z*wv.z + xv.w*wv.w;
    }
    x2[i] = acc;
    // zero frag pads: s=5 block, d=84..87 -> (hf=0,j=4..7); d=88..95 -> (hf=1,j=0..7)
    int bh = i >> 10;
    size_t base = (size_t)(bh*32 + (n >> 5))*3072 + 5*512 + (n & 31)*8;
    ushort4 z = make_ushort4(0,0,0,0);
    *(ushort4*)(qf + base + 4)       = z;
    *(ushort4*)(qf + base + 256)     = z;
    *(ushort4*)(qf + base + 256 + 4) = z;
    *(ushort4*)(kf + base + 4)       = z;
    *(ushort4*)(kf + base + 256)     = z;
    *(ushort4*)(kf + base + 256 + 4) = z;
}

// ---------------- Kernel C: per-(b,h) avg+max pool ----------------
__global__ __launch_bounds__(256)
void pool_kernel(const float* __restrict__ x2, float* __restrict__ spool)
{
    int bh = blockIdx.x;
    int t = threadIdx.x;
    const float* p = x2 + (size_t)bh*NN;
    float s = 0.f, mx = -INFINITY;
    for (int i = t; i < NN; i += 256) { float v = p[i]; s += v; mx = fmaxf(mx, v); }
#pragma unroll
    for (int off = 1; off < 64; off <<= 1) {
        s  += __shfl_xor(s, off);
        mx  = fmaxf(mx, __shfl_xor(mx, off));
    }
    __shared__ float rs[4], rm[4];
    int w = t >> 6;
    if ((t & 63) == 0) { rs[w] = s; rm[w] = mx; }
    __syncthreads();
    if (t == 0) {
        float ss = rs[0]+rs[1]+rs[2]+rs[3];
        float mm = fmaxf(fmaxf(rm[0],rm[1]), fmaxf(rm[2],rm[3]));
        spool[bh] = ss * (1.f/1024.f) + mm;
    }
}

// ---------------- Kernel D: depthwise conv + pooled, batch-mean -> xw, xp ----------------
__global__ __launch_bounds__(256)
void lspe_kernel(const float* __restrict__ x2, const float* __restrict__ spool,
                 const float* __restrict__ Wdw, const float* __restrict__ bdw,
                 float* __restrict__ xw, float* __restrict__ xp)
{
    int i = blockIdx.x*256 + threadIdx.x;
    int h = i >> 10;
    int n = i & 1023;
    int y = n >> 5, xx = n & 31;
    int g0 = h >> 1;
    float accW = 0.f, accP = 0.f;
    for (int b = 0; b < 4; b++) {
        float sp = spool[b*8 + h];
        float c0 = bdw[h], c1 = bdw[8 + h];
        const float* a0 = x2 + (size_t)(b*8 + g0)*NN;
        const float* a1 = x2 + (size_t)(b*8 + 4 + g0)*NN;
#pragma unroll
        for (int ky = 0; ky < 3; ky++) {
            int yy = y + ky - 1;
            if (yy < 0 || yy > 31) continue;
#pragma unroll
            for (int kx = 0; kx < 3; kx++) {
                int xc = xx + kx - 1;
                if (xc < 0 || xc > 31) continue;
                c0 += a0[yy*32 + xc] * Wdw[h*9 + ky*3 + kx];
                c1 += a1[yy*32 + xc] * Wdw[(8+h)*9 + ky*3 + kx];
            }
        }
        accW += c0 + sp;
        accP += c1 + sp;
    }
    xw[i] = 0.25f * accW;
    xp[i] = 0.25f * accP;
}

// ---------------- Kernel E: correlation -> 63x63 bias table + per-head global max ----------------
__global__ __launch_bounds__(256)
void bias_kernel(const float* __restrict__ xw, const float* __restrict__ xp,
                 float* __restrict__ btab, unsigned* __restrict__ Mg)
{
    __shared__ float sxw[1024], sxp[1024];
    int h = blockIdx.y;
    int t = threadIdx.x;
    for (int i = t; i < 1024; i += 256) { sxw[i] = xw[h*1024+i]; sxp[i] = xp[h*1024+i]; }
    __syncthreads();
    int p = blockIdx.x*256 + t;
    int oy = p / 63, ox = p - oy*63;
    int alo = max(0, oy-31), ahi = min(31, oy);
    int clo = max(0, ox-31), chi = min(31, ox);
    float acc = 0.f;
    for (int a = alo; a <= ahi; a++)
        for (int c = clo; c <= chi; c++)
            acc += sxp[a*32 + c] * sxw[(oy-a)*32 + (ox-c)];
    unsigned key = 0u;
    if (p < 3969) {
        btab[h*3969 + p] = acc;
        unsigned u = __float_as_uint(acc);
        key = (u & 0x80000000u) ? ~u : (u | 0x80000000u);
    }
#pragma unroll
    for (int off = 1; off < 64; off <<= 1) {
        unsigned o = __shfl_xor(key, off);
        key = key > o ? key : o;
    }
    if ((t & 63) == 0) atomicMax(Mg + h, key);
}

// ---------------- Kernel F: barrier-free MFMA flash attention, coalesced frag-linear loads ----------------
// grid 1024: bh = bid&31 (XCD-local), qt = bid>>5; 4 independent waves, wave w owns kt = 4j+w.
__global__ __launch_bounds__(256, 2)
void attn_kernel(const ushort* __restrict__ qg, const ushort* __restrict__ kg,
                 const ushort* __restrict__ vg, const float* __restrict__ btg,
                 const unsigned* __restrict__ Mg, float* __restrict__ Obuf)
{
    __shared__ float btabS[2016];        // 32 table rows for this q y-row
    __shared__ float red[2][64*52];
    __shared__ float lred[32];

    int t = threadIdx.x;
    int bid = blockIdx.x;
    int bh = bid & 31, qt = bid >> 5;
    int h = bh & 7, b = bh >> 3;
    int q0 = qt * 32;

    float Mh;
    { unsigned k = Mg[h]; unsigned u = (k & 0x80000000u) ? (k ^ 0x80000000u) : ~k; Mh = __uint_as_float(u); }
    const float* bsrc = btg + h*3969 + qt*63;      // rows yq .. yq+31
    for (int i = t; i < 2016; i += 256) btabS[i] = bsrc[i] - Mh;
    __syncthreads();

    int w = t >> 6, lane = t & 63, col = lane & 31, half = lane >> 5;
    int lofs = half*256 + col*8;

    // loop-invariant Q B-frags
    bf16x8 bq6[6];
    const ushort* qbase = qg + (size_t)(bh*32 + qt)*3072 + lofs;
#pragma unroll
    for (int s = 0; s < 6; s++) bq6[s] = *(const bf16x8*)(qbase + s*512);

    f32x16 of[3];
#pragma unroll
    for (int f = 0; f < 3; f++)
#pragma unroll
        for (int r = 0; r < 16; r++) of[f][r] = 0.f;

    int kx_[16];
#pragma unroll
    for (int r = 0; r < 16; r++) kx_[r] = qxmap(r, half);

    const ushort* kall = kg + (size_t)bh*32*3072 + lofs;
    const ushort* vall = vg + (size_t)bh*32*3072 + lofs;

    bf16x8 akc[6];
    {
        const ushort* kr = kall + (size_t)w*3072;
#pragma unroll
        for (int s = 0; s < 6; s++) akc[s] = *(const bf16x8*)(kr + s*512);
    }

    for (int j = 0; j < 8; j++) {
        int kt = 4*j + w;
        // V B-frags — issued early, consumed after softmax
        const ushort* vr = vall + (size_t)kt*3072;
        bf16x8 vfr[3][2];
#pragma unroll
        for (int f = 0; f < 3; f++)
#pragma unroll
            for (int c = 0; c < 2; c++)
                vfr[f][c] = *(const bf16x8*)(vr + f*1024 + c*512);

        // St = K.Q^T : D[m=key][n=q]
        f32x16 st;
#pragma unroll
        for (int r = 0; r < 16; r++) st[r] = 0.f;
#pragma unroll
        for (int s = 0; s < 6; s++)
            st = __builtin_amdgcn_mfma_f32_32x32x16_bf16(akc[s], bq6[s], st, 0, 0, 0);

        // prefetch next K tile
        bf16x8 akn[6];
        if (j < 7) {
            const ushort* kr = kall + (size_t)(kt + 4)*3072;
#pragma unroll
            for (int s = 0; s < 6; s++) akn[s] = *(const bf16x8*)(kr + s*512);
        }

        // P = exp(st + bias - M), packed to bf16 pairs (round-half-up)
        const float* bp = btabS + (31 - kt)*63 + col + 31;
        unsigned P[8];
#pragma unroll
        for (int g = 0; g < 8; g++) {
            float p0 = __expf(st[2*g]   + bp[-kx_[2*g]]);
            float p1 = __expf(st[2*g+1] + bp[-kx_[2*g+1]]);
            unsigned u0 = __float_as_uint(p0) + 0x8000u;
            unsigned u1 = __float_as_uint(p1) + 0x8000u;
            P[g] = (u1 & 0xFFFF0000u) | (u0 >> 16);
        }
        unsigned XP[8];
#pragma unroll
        for (int g = 0; g < 8; g++) XP[g] = (unsigned)__shfl_xor((int)P[g], 32);

        union { bf16x8 v; unsigned u[4]; } f0, f1;
        f0.u[0] = half ? XP[2] : P[0];
        f0.u[1] = half ? XP[3] : P[1];
        f0.u[2] = half ? P[2]  : XP[0];
        f0.u[3] = half ? P[3]  : XP[1];
        f1.u[0] = half ? XP[6] : P[4];
        f1.u[1] = half ? XP[7] : P[5];
        f1.u[2] = half ? P[6]  : XP[4];
        f1.u[3] = half ? P[7]  : XP[5];

        // O += P.V ; l accumulates via ones-row d=84
#pragma unroll
        for (int f = 0; f < 3; f++) {
            of[f] = __builtin_amdgcn_mfma_f32_32x32x16_bf16(f0.v, vfr[f][0], of[f], 0, 0, 0);
            of[f] = __builtin_amdgcn_mfma_f32_32x32x16_bf16(f1.v, vfr[f][1], of[f], 0, 0, 0);
        }
        if (j < 7) {
#pragma unroll
            for (int s = 0; s < 6; s++) akc[s] = akn[s];
        }
    }

    // ---- 4-way O reduction (tree) + epilogue ----
    __syncthreads();
    if (w == 1 || w == 3) {
        float* dst = red[w >> 1] + lane*52;
#pragma unroll
        for (int f = 0; f < 3; f++)
#pragma unroll
            for (int r = 0; r < 16; r++) dst[f*16 + r] = of[f][r];
    }
    __syncthreads();
    if (w == 0 || w == 2) {
        const float* src = red[w >> 1] + lane*52;
#pragma unroll
        for (int f = 0; f < 3; f++)
#pragma unroll
            for (int r = 0; r < 16; r++) of[f][r] += src[f*16 + r];
    }
    __syncthreads();
    if (w == 2) {
        float* dst = red[0] + lane*52;
#pragma unroll
        for (int f = 0; f < 3; f++)
#pragma unroll
            for (int r = 0; r < 16; r++) dst[f*16 + r] = of[f][r];
    }
    __syncthreads();
    if (w == 0) {
        const float* src = red[0] + lane*52;
#pragma unroll
        for (int f = 0; f < 3; f++)
#pragma unroll
            for (int r = 0; r < 16; r++) of[f][r] += src[f*16 + r];
        if (col == 20) {
#pragma unroll
            for (int r = 0; r < 16; r++) lred[qxmap(r, half)] = of[2][r];
        }
    }
    __syncthreads();
    if (w == 0) {
        float linv[16];
#pragma unroll
        for (int r = 0; r < 16; r++) linv[r] = 1.0f / lred[qxmap(r, half)];
#pragma unroll
        for (int f = 0; f < 3; f++) {
            int d = f*32 + col;
            if (d < DD) {
                int m = d >> 2, dd2 = d & 3;
#pragma unroll
                for (int r = 0; r < 16; r++) {
                    int q = qxmap(r, half);
                    size_t R = ((size_t)(b*NN + q0 + q))*21 + m;
                    Obuf[R*32 + h*4 + dd2] = of[f][r] * linv[r];
                }
            }
        }
    }
}

// ---------------- Kernel G: output projection via MFMA (LDS-staged activations) ----------------
__global__ __launch_bounds__(256)
void proj_kernel(const float* __restrict__ Obuf, const float* __restrict__ Wp,
                 const float* __restrict__ bp, float* __restrict__ out)
{
    __shared__ ushort wps[1024];
    __shared__ float bps[32];
    __shared__ __align__(16) float os[128*36];
    int t = threadIdx.x;
    int w = t >> 6, lane = t & 63, col = lane & 31, half = lane >> 5;
    int R0 = blockIdx.x * 128;
    for (int i = t; i < 1024; i += 256) wps[i] = f2bf(Wp[i]);
    if (t < 32) bps[t] = bp[t];
    for (int i = t; i < 4096; i += 256)
        os[(i >> 5)*36 + (i & 31)] = Obuf[(size_t)R0*32 + i];
    __syncthreads();

    bf16x8 bw[2];
#pragma unroll
    for (int c = 0; c < 2; c++) {
        union { bf16x8 v; ushort s[8]; } u;
#pragma unroll
        for (int j = 0; j < 8; j++)
            u.s[j] = wps[(c*16 + half*8 + j)*32 + col];
        bw[c] = u.v;
    }
    bf16x8 aw[2];
#pragma unroll
    for (int c = 0; c < 2; c++) {
        const float* orr = os + (w*32 + col)*36 + c*16 + half*8;
        float4 v0 = *(const float4*)(orr);
        float4 v1 = *(const float4*)(orr + 4);
        union { bf16x8 v; ushort s[8]; } u;
        u.s[0]=f2bf(v0.x); u.s[1]=f2bf(v0.y); u.s[2]=f2bf(v0.z); u.s[3]=f2bf(v0.w);
        u.s[4]=f2bf(v1.x); u.s[5]=f2bf(v1.y); u.s[6]=f2bf(v1.z); u.s[7]=f2bf(v1.w);
        aw[c] = u.v;
    }
    f32x16 acc;
#pragma unroll
    for (int r = 0; r < 16; r++) acc[r] = 0.f;
#pragma unroll
    for (int c = 0; c < 2; c++)
        acc = __builtin_amdgcn_mfma_f32_32x32x16_bf16(aw[c], bw[c], acc, 0, 0, 0);
    float bb = bps[col];
#pragma unroll
    for (int r = 0; r < 16; r++)
        out[(size_t)(R0 + w*32 + qxmap(r, half))*32 + col] = acc[r] + bb;
}

extern "C" void kernel_launch(void* const* d_in, const int* in_sizes, int n_in,
                              void* d_out, int out_size, void* d_ws, size_t ws_size,
                              hipStream_t stream)
{
    const float* x     = (const float*)d_in[0];
    const float* Wqkv  = (const float*)d_in[1];
    const float* bqkv  = (const float*)d_in[2];
    const float* Wproj = (const float*)d_in[3];
    const float* bproj = (const float*)d_in[4];
    const float* Wsq   = (const float*)d_in[5];
    const float* bsq   = (const float*)d_in[6];
    const float* Wdw   = (const float*)d_in[7];
    const float* bdw   = (const float*)d_in[8];

    const size_t QP = (size_t)BN * NN * DP;   // 3,145,728
    const size_t VB = (size_t)BN * NN * DD;   // 2,752,512
    ushort* qf   = (ushort*)d_ws;
    ushort* kf   = qf + QP;
    ushort* vb   = kf + QP;
    ushort* vf   = vb + VB;
    float* Obuf  = (float*)(vf + QP);
    float* x2    = Obuf + VB;
    float* spool = x2 + 32768;
    float* xw    = spool + 32;
    float* xp    = xw + 8192;
    float* btab  = xp + 8192;
    unsigned* Mg = (unsigned*)(btab + 3969*8);
    float* out   = (float*)d_out;

    qkv_kernel <<<NROWS/128, 256, 0, stream>>>(x, Wqkv, bqkv, qf, kf, vb);
    vtr_kernel <<<dim3(16,32),256, 0, stream>>>(vb, vf);
    x2_kernel  <<<128,        256, 0, stream>>>(x, Wsq, bsq, x2, Mg, qf, kf);
    pool_kernel<<<32,         256, 0, stream>>>(x2, spool);
    lspe_kernel<<<32,         256, 0, stream>>>(x2, spool, Wdw, bdw, xw, xp);
    bias_kernel<<<dim3(16,8), 256, 0, stream>>>(xw, xp, btab, Mg);
    attn_kernel<<<1024,       256, 0, stream>>>(qf, kf, vf, btab, Mg, Obuf);
    proj_kernel<<<NROWS/128,  256, 0, stream>>>(Obuf, Wproj, bproj, out);
}

// Round 6
// 161.212 us; speedup vs baseline: 3.2351x; 1.2061x over previous
//
#include <hip/hip_runtime.h>
#include <math.h>

#define NHEAD 8
#define BATCH 4
#define NN 1024              // H*W
#define MM 21
#define DD 84                // M*hd
#define DP 96                // padded feature dim
#define BN (BATCH*NHEAD)     // 32
#define NROWS (BATCH*NN*MM)  // 86016

typedef __attribute__((ext_vector_type(8))) short bf16x8;
typedef __attribute__((ext_vector_type(16))) float f32x16;

__device__ __forceinline__ unsigned short f2bf(float x) {
    union { float f; unsigned int u; } c; c.f = x;
    unsigned int r = (c.u + 0x7FFFu + ((c.u >> 16) & 1u)) >> 16;
    return (unsigned short)r;
}
__device__ __forceinline__ int qxmap(int r, int half) { return (r & 3) + 8*(r >> 2) + 4*half; }

// Fragment-linear layouts (ushort):
//  Qf/Kf: addr(bh,n,d) = ((bh*32 + n/32)*6 + d/16)*512 + ((d>>3)&1)*256 + (n&31)*8 + (d&7)
//  Vf:    addr(bh,n,d) = (bh*32 + n/32)*3072 + (d/32)*1024 + ((n>>4)&1)*512 + ((n>>3)&1)*256 + (d&31)*8 + (n&7)

// ---------------- Kernel A: qkv projection via MFMA -> Qf,Kf frag-layout (q pre-scaled), v row-major [bh][n][84] ----------------
__global__ __launch_bounds__(256)
void qkv_kernel(const float* __restrict__ x, const float* __restrict__ Wq,
                const float* __restrict__ bq, ushort* __restrict__ qf,
                ushort* __restrict__ kf, ushort* __restrict__ vb)
{
    __shared__ ushort wqs[3072];
    __shared__ float bqs[96];
    __shared__ __align__(16) float xs[128*36];
    __shared__ ushort cs[4*3200];      // per-wave 32x(96+4) repack
    int t = threadIdx.x;
    int w = t >> 6, lane = t & 63, col = lane & 31, half = lane >> 5;
    int R0 = blockIdx.x * 128;

    for (int i = t; i < 3072; i += 256) wqs[i] = f2bf(Wq[i]);
    if (t < 96) bqs[t] = bq[t];
    for (int i = t; i < 4096; i += 256)
        xs[(i >> 5)*36 + (i & 31)] = x[(size_t)R0*32 + i];
    __syncthreads();

    bf16x8 bw[3][2];
#pragma unroll
    for (int f = 0; f < 3; f++)
#pragma unroll
        for (int c = 0; c < 2; c++) {
            union { bf16x8 v; ushort s[8]; } u;
#pragma unroll
            for (int j = 0; j < 8; j++)
                u.s[j] = wqs[(c*16 + half*8 + j)*96 + f*32 + col];
            bw[f][c] = u.v;
        }
    bf16x8 aw[2];
#pragma unroll
    for (int c = 0; c < 2; c++) {
        const float* xr = xs + (w*32 + col)*36 + c*16 + half*8;
        float4 v0 = *(const float4*)(xr);
        float4 v1 = *(const float4*)(xr + 4);
        union { bf16x8 v; ushort s[8]; } u;
        u.s[0]=f2bf(v0.x); u.s[1]=f2bf(v0.y); u.s[2]=f2bf(v0.z); u.s[3]=f2bf(v0.w);
        u.s[4]=f2bf(v1.x); u.s[5]=f2bf(v1.y); u.s[6]=f2bf(v1.z); u.s[7]=f2bf(v1.w);
        aw[c] = u.v;
    }
    f32x16 acc[3];
#pragma unroll
    for (int f = 0; f < 3; f++) {
#pragma unroll
        for (int r = 0; r < 16; r++) acc[f][r] = 0.f;
#pragma unroll
        for (int c = 0; c < 2; c++)
            acc[f] = __builtin_amdgcn_mfma_f32_32x32x16_bf16(aw[c], bw[f][c], acc[f], 0, 0, 0);
    }
    ushort* myc = cs + w*3200;
#pragma unroll
    for (int f = 0; f < 3; f++) {
        float sc = (f == 0) ? 0.03125f : 1.0f;   // fold qk scale into q
        float bb = bqs[f*32 + col];
#pragma unroll
        for (int r = 0; r < 16; r++)
            myc[qxmap(r, half)*100 + f*32 + col] = f2bf((acc[f][r] + bb)*sc);
    }
    __syncthreads();
    int row = lane >> 1, hr = lane & 1;
    int Rr = R0 + w*32 + row;
    int b_ = Rr / 21, m = Rr - b_*21, b = b_ >> 10, n = b_ & 1023;
    size_t fragoff = (size_t)(m >> 2)*512 + ((m >> 1) & 1)*256 + (n & 31)*8 + ((4*m) & 7);
    int nt = n >> 5;
#pragma unroll
    for (int c2 = 0; c2 < 12; c2++) {
        int col4 = hr*48 + c2*4;
        ushort4 v = *(const ushort4*)(myc + row*100 + col4);
        int s = col4 >> 5, hh = (col4 & 31) >> 2;
        if (s == 0)
            *(ushort4*)(qf + (size_t)((b*8 + hh)*32 + nt)*3072 + fragoff) = v;
        else if (s == 1)
            *(ushort4*)(kf + (size_t)((b*8 + hh)*32 + nt)*3072 + fragoff) = v;
        else
            *(ushort4*)(vb + ((size_t)((b*8 + hh)*1024 + n))*DD + m*4) = v;
    }
}

// ---------------- Kernel A2: v [bh][n][84] -> Vf frag layout (d=84 ones, 85..95 zero) ----------------
__global__ __launch_bounds__(256)
void vtr_kernel(const ushort* __restrict__ vb, ushort* __restrict__ vf)
{
    __shared__ ushort ld[64*88];
    int t = threadIdx.x;
    int bh = blockIdx.y, n0 = blockIdx.x * 64;
    for (int i = t; i < 1344; i += 256) {
        int r = i/21, p = i - r*21;
        *(ushort4*)(ld + r*88 + p*4) = *(const ushort4*)(vb + ((size_t)bh*NN + n0 + r)*DD + p*4);
    }
    __syncthreads();
    for (int j = t; j < 1344; j += 256) {
        int d = j >> 4, g = j & 15;
        ushort4 wv;
        wv.x = ld[(g*4+0)*88 + d]; wv.y = ld[(g*4+1)*88 + d];
        wv.z = ld[(g*4+2)*88 + d]; wv.w = ld[(g*4+3)*88 + d];
        int nn = n0 + g*4;
        size_t addr = (size_t)(bh*32 + (nn >> 5))*3072 + (d >> 5)*1024
                    + ((nn >> 4) & 1)*512 + ((nn >> 3) & 1)*256 + (d & 31)*8 + (nn & 7);
        *(ushort4*)(vf + addr) = wv;
    }
    if (t < 192) {
        int r = 84 + t/16, p = t & 15;
        int nn = n0 + p*4;
        ushort e = (r == 84) ? (ushort)0x3F80 : (ushort)0;
        size_t addr = (size_t)(bh*32 + (nn >> 5))*3072 + 2*1024
                    + ((nn >> 4) & 1)*512 + ((nn >> 3) & 1)*256 + (r & 31)*8 + (nn & 7);
        *(ushort4*)(vf + addr) = make_ushort4(e, e, e, e);
    }
}

// ---------------- Kernel B: x2 = x . W_sq + b_sq ; init Mg ; zero q/k frag pads (d=84..95) ----------------
__global__ __launch_bounds__(256)
void x2_kernel(const float* __restrict__ x, const float* __restrict__ Wsq,
               const float* __restrict__ bsq, float* __restrict__ x2,
               unsigned* __restrict__ Mg, ushort* __restrict__ qf,
               ushort* __restrict__ kf)
{
    __shared__ __align__(16) float ws[84];
    int t = threadIdx.x;
    if (t < 84) ws[t] = Wsq[t];
    if (blockIdx.x == 0 && t < 8) Mg[t] = 0u;
    __syncthreads();
    int i = blockIdx.x * 256 + t;        // (b*8+h)*1024 + n
    int b = i >> 13;
    int h = (i >> 10) & 7;
    int n = i & 1023;
    const float* xr = x + ((size_t)(b*NN + n))*672 + h*4;
    float acc = bsq[0];
#pragma unroll
    for (int m = 0; m < 21; m++) {
        float4 xv = *(const float4*)(xr + m*32);
        float4 wv = *(const float4*)(ws + m*4);
        acc += xv.x*wv.x + xv.y*wv.y + xv.z*wv.z + xv.w*wv.w;
    }
    x2[i] = acc;
    int bh = i >> 10;
    size_t base = (size_t)(bh*32 + (n >> 5))*3072 + 5*512 + (n & 31)*8;
    ushort4 z = make_ushort4(0,0,0,0);
    *(ushort4*)(qf + base + 4)       = z;
    *(ushort4*)(qf + base + 256)     = z;
    *(ushort4*)(qf + base + 256 + 4) = z;
    *(ushort4*)(kf + base + 4)       = z;
    *(ushort4*)(kf + base + 256)     = z;
    *(ushort4*)(kf + base + 256 + 4) = z;
}

// ---------------- Kernel C: per-(b,h) avg+max pool ----------------
__global__ __launch_bounds__(256)
void pool_kernel(const float* __restrict__ x2, float* __restrict__ spool)
{
    int bh = blockIdx.x;
    int t = threadIdx.x;
    const float* p = x2 + (size_t)bh*NN;
    float s = 0.f, mx = -INFINITY;
    for (int i = t; i < NN; i += 256) { float v = p[i]; s += v; mx = fmaxf(mx, v); }
#pragma unroll
    for (int off = 1; off < 64; off <<= 1) {
        s  += __shfl_xor(s, off);
        mx  = fmaxf(mx, __shfl_xor(mx, off));
    }
    __shared__ float rs[4], rm[4];
    int w = t >> 6;
    if ((t & 63) == 0) { rs[w] = s; rm[w] = mx; }
    __syncthreads();
    if (t == 0) {
        float ss = rs[0]+rs[1]+rs[2]+rs[3];
        float mm = fmaxf(fmaxf(rm[0],rm[1]), fmaxf(rm[2],rm[3]));
        spool[bh] = ss * (1.f/1024.f) + mm;
    }
}

// ---------------- Kernel D: depthwise conv + pooled, batch-mean -> xw, xp ----------------
__global__ __launch_bounds__(256)
void lspe_kernel(const float* __restrict__ x2, const float* __restrict__ spool,
                 const float* __restrict__ Wdw, const float* __restrict__ bdw,
                 float* __restrict__ xw, float* __restrict__ xp)
{
    int i = blockIdx.x*256 + threadIdx.x;
    int h = i >> 10;
    int n = i & 1023;
    int y = n >> 5, xx = n & 31;
    int g0 = h >> 1;
    float accW = 0.f, accP = 0.f;
    for (int b = 0; b < 4; b++) {
        float sp = spool[b*8 + h];
        float c0 = bdw[h], c1 = bdw[8 + h];
        const float* a0 = x2 + (size_t)(b*8 + g0)*NN;
        const float* a1 = x2 + (size_t)(b*8 + 4 + g0)*NN;
#pragma unroll
        for (int ky = 0; ky < 3; ky++) {
            int yy = y + ky - 1;
            if (yy < 0 || yy > 31) continue;
#pragma unroll
            for (int kx = 0; kx < 3; kx++) {
                int xc = xx + kx - 1;
                if (xc < 0 || xc > 31) continue;
                c0 += a0[yy*32 + xc] * Wdw[h*9 + ky*3 + kx];
                c1 += a1[yy*32 + xc] * Wdw[(8+h)*9 + ky*3 + kx];
            }
        }
        accW += c0 + sp;
        accP += c1 + sp;
    }
    xw[i] = 0.25f * accW;
    xp[i] = 0.25f * accP;
}

// ---------------- Kernel E: correlation -> 63x63 bias table + per-head global max ----------------
// grid (63, 8) = (oy, h); 512 threads: t = aw*64 + ox, aw in [0,8) splits the a-sum.
__global__ __launch_bounds__(512)
void bias_kernel(const float* __restrict__ xw, const float* __restrict__ xp,
                 float* __restrict__ btab, unsigned* __restrict__ Mg)
{
    __shared__ float sxw[1024], sxp[1024];
    __shared__ float part[8][64];
    int h = blockIdx.y, oy = blockIdx.x;
    int t = threadIdx.x;
    for (int i = t; i < 1024; i += 512) { sxw[i] = xw[h*1024+i]; sxp[i] = xp[h*1024+i]; }
    __syncthreads();
    int ox = t & 63;           // 63 valid outputs; ox==63 idle
    int aw = t >> 6;           // 0..7
    int alo = max(0, oy-31), ahi = min(31, oy);
    int clo = max(0, ox-31), chi = min(31, ox);
    int cnt = chi - clo + 1;   // 1..32 (ox<63)
    float acc0 = 0.f, acc1 = 0.f;
    if (ox < 63) {
        for (int a = alo + aw; a <= ahi; a += 8) {
            const float* prow = sxp + a*32 + clo;
            const float* wrow = sxw + (oy - a)*32 + (ox - clo);
            int k = 0;
            for (; k + 1 < cnt; k += 2) {
                acc0 += prow[k]   * wrow[-k];
                acc1 += prow[k+1] * wrow[-k-1];
            }
            if (k < cnt) acc0 += prow[k] * wrow[-k];
        }
    }
    part[aw][ox] = acc0 + acc1;
    __syncthreads();
    if (t < 64) {
        float acc = 0.f;
#pragma unroll
        for (int j = 0; j < 8; j++) acc += part[j][t];
        unsigned key = 0u;
        if (t < 63) {
            btab[h*3969 + oy*63 + t] = acc;
            unsigned u = __float_as_uint(acc);
            key = (u & 0x80000000u) ? ~u : (u | 0x80000000u);
        }
#pragma unroll
        for (int off = 1; off < 64; off <<= 1) {
            unsigned o = __shfl_xor(key, off);
            key = key > o ? key : o;
        }
        if (t == 0) atomicMax(Mg + h, key);
    }
}

// ---------------- Kernel F: barrier-free MFMA flash attention, coalesced frag-linear loads ----------------
// grid 1024: bh = bid&31 (XCD-local), qt = bid>>5; 4 independent waves, wave w owns kt = 4j+w.
__global__ __launch_bounds__(256, 2)
void attn_kernel(const ushort* __restrict__ qg, const ushort* __restrict__ kg,
                 const ushort* __restrict__ vg, const float* __restrict__ btg,
                 const unsigned* __restrict__ Mg, float* __restrict__ Obuf)
{
    __shared__ float btabS[2016];        // 32 table rows for this q y-row
    __shared__ float red[2][64*52];
    __shared__ float lred[32];

    int t = threadIdx.x;
    int bid = blockIdx.x;
    int bh = bid & 31, qt = bid >> 5;
    int h = bh & 7, b = bh >> 3;
    int q0 = qt * 32;

    float Mh;
    { unsigned k = Mg[h]; unsigned u = (k & 0x80000000u) ? (k ^ 0x80000000u) : ~k; Mh = __uint_as_float(u); }
    const float* bsrc = btg + h*3969 + qt*63;      // rows yq .. yq+31
    for (int i = t; i < 2016; i += 256) btabS[i] = bsrc[i] - Mh;
    __syncthreads();

    int w = t >> 6, lane = t & 63, col = lane & 31, half = lane >> 5;
    int lofs = half*256 + col*8;

    bf16x8 bq6[6];
    const ushort* qbase = qg + (size_t)(bh*32 + qt)*3072 + lofs;
#pragma unroll
    for (int s = 0; s < 6; s++) bq6[s] = *(const bf16x8*)(qbase + s*512);

    f32x16 of[3];
#pragma unroll
    for (int f = 0; f < 3; f++)
#pragma unroll
        for (int r = 0; r < 16; r++) of[f][r] = 0.f;

    int kx_[16];
#pragma unroll
    for (int r = 0; r < 16; r++) kx_[r] = qxmap(r, half);

    const ushort* kall = kg + (size_t)bh*32*3072 + lofs;
    const ushort* vall = vg + (size_t)bh*32*3072 + lofs;

    bf16x8 akc[6];
    {
        const ushort* kr = kall + (size_t)w*3072;
#pragma unroll
        for (int s = 0; s < 6; s++) akc[s] = *(const bf16x8*)(kr + s*512);
    }

    for (int j = 0; j < 8; j++) {
        int kt = 4*j + w;
        const ushort* vr = vall + (size_t)kt*3072;
        bf16x8 vfr[3][2];
#pragma unroll
        for (int f = 0; f < 3; f++)
#pragma unroll
            for (int c = 0; c < 2; c++)
                vfr[f][c] = *(const bf16x8*)(vr + f*1024 + c*512);

        f32x16 st;
#pragma unroll
        for (int r = 0; r < 16; r++) st[r] = 0.f;
#pragma unroll
        for (int s = 0; s < 6; s++)
            st = __builtin_amdgcn_mfma_f32_32x32x16_bf16(akc[s], bq6[s], st, 0, 0, 0);

        bf16x8 akn[6];
        if (j < 7) {
            const ushort* kr = kall + (size_t)(kt + 4)*3072;
#pragma unroll
            for (int s = 0; s < 6; s++) akn[s] = *(const bf16x8*)(kr + s*512);
        }

        const float* bp = btabS + (31 - kt)*63 + col + 31;
        unsigned P[8];
#pragma unroll
        for (int g = 0; g < 8; g++) {
            float p0 = __expf(st[2*g]   + bp[-kx_[2*g]]);
            float p1 = __expf(st[2*g+1] + bp[-kx_[2*g+1]]);
            unsigned u0 = __float_as_uint(p0) + 0x8000u;
            unsigned u1 = __float_as_uint(p1) + 0x8000u;
            P[g] = (u1 & 0xFFFF0000u) | (u0 >> 16);
        }
        unsigned XP[8];
#pragma unroll
        for (int g = 0; g < 8; g++) XP[g] = (unsigned)__shfl_xor((int)P[g], 32);

        union { bf16x8 v; unsigned u[4]; } f0, f1;
        f0.u[0] = half ? XP[2] : P[0];
        f0.u[1] = half ? XP[3] : P[1];
        f0.u[2] = half ? P[2]  : XP[0];
        f0.u[3] = half ? P[3]  : XP[1];
        f1.u[0] = half ? XP[6] : P[4];
        f1.u[1] = half ? XP[7] : P[5];
        f1.u[2] = half ? P[6]  : XP[4];
        f1.u[3] = half ? P[7]  : XP[5];

#pragma unroll
        for (int f = 0; f < 3; f++) {
            of[f] = __builtin_amdgcn_mfma_f32_32x32x16_bf16(f0.v, vfr[f][0], of[f], 0, 0, 0);
            of[f] = __builtin_amdgcn_mfma_f32_32x32x16_bf16(f1.v, vfr[f][1], of[f], 0, 0, 0);
        }
        if (j < 7) {
#pragma unroll
            for (int s = 0; s < 6; s++) akc[s] = akn[s];
        }
    }

    // ---- 4-way O reduction (tree) + epilogue ----
    __syncthreads();
    if (w == 1 || w == 3) {
        float* dst = red[w >> 1] + lane*52;
#pragma unroll
        for (int f = 0; f < 3; f++)
#pragma unroll
            for (int r = 0; r < 16; r++) dst[f*16 + r] = of[f][r];
    }
    __syncthreads();
    if (w == 0 || w == 2) {
        const float* src = red[w >> 1] + lane*52;
#pragma unroll
        for (int f = 0; f < 3; f++)
#pragma unroll
            for (int r = 0; r < 16; r++) of[f][r] += src[f*16 + r];
    }
    __syncthreads();
    if (w == 2) {
        float* dst = red[0] + lane*52;
#pragma unroll
        for (int f = 0; f < 3; f++)
#pragma unroll
            for (int r = 0; r < 16; r++) dst[f*16 + r] = of[f][r];
    }
    __syncthreads();
    if (w == 0) {
        const float* src = red[0] + lane*52;
#pragma unroll
        for (int f = 0; f < 3; f++)
#pragma unroll
            for (int r = 0; r < 16; r++) of[f][r] += src[f*16 + r];
        if (col == 20) {
#pragma unroll
            for (int r = 0; r < 16; r++) lred[qxmap(r, half)] = of[2][r];
        }
    }
    __syncthreads();
    if (w == 0) {
        float linv[16];
#pragma unroll
        for (int r = 0; r < 16; r++) linv[r] = 1.0f / lred[qxmap(r, half)];
#pragma unroll
        for (int f = 0; f < 3; f++) {
            int d = f*32 + col;
            if (d < DD) {
                int m = d >> 2, dd2 = d & 3;
#pragma unroll
                for (int r = 0; r < 16; r++) {
                    int q = qxmap(r, half);
                    size_t R = ((size_t)(b*NN + q0 + q))*21 + m;
                    Obuf[R*32 + h*4 + dd2] = of[f][r] * linv[r];
                }
            }
        }
    }
}

// ---------------- Kernel G: output projection via MFMA (LDS-staged activations) ----------------
__global__ __launch_bounds__(256)
void proj_kernel(const float* __restrict__ Obuf, const float* __restrict__ Wp,
                 const float* __restrict__ bp, float* __restrict__ out)
{
    __shared__ ushort wps[1024];
    __shared__ float bps[32];
    __shared__ __align__(16) float os[128*36];
    int t = threadIdx.x;
    int w = t >> 6, lane = t & 63, col = lane & 31, half = lane >> 5;
    int R0 = blockIdx.x * 128;
    for (int i = t; i < 1024; i += 256) wps[i] = f2bf(Wp[i]);
    if (t < 32) bps[t] = bp[t];
    for (int i = t; i < 4096; i += 256)
        os[(i >> 5)*36 + (i & 31)] = Obuf[(size_t)R0*32 + i];
    __syncthreads();

    bf16x8 bw[2];
#pragma unroll
    for (int c = 0; c < 2; c++) {
        union { bf16x8 v; ushort s[8]; } u;
#pragma unroll
        for (int j = 0; j < 8; j++)
            u.s[j] = wps[(c*16 + half*8 + j)*32 + col];
        bw[c] = u.v;
    }
    bf16x8 aw[2];
#pragma unroll
    for (int c = 0; c < 2; c++) {
        const float* orr = os + (w*32 + col)*36 + c*16 + half*8;
        float4 v0 = *(const float4*)(orr);
        float4 v1 = *(const float4*)(orr + 4);
        union { bf16x8 v; ushort s[8]; } u;
        u.s[0]=f2bf(v0.x); u.s[1]=f2bf(v0.y); u.s[2]=f2bf(v0.z); u.s[3]=f2bf(v0.w);
        u.s[4]=f2bf(v1.x); u.s[5]=f2bf(v1.y); u.s[6]=f2bf(v1.z); u.s[7]=f2bf(v1.w);
        aw[c] = u.v;
    }
    f32x16 acc;
#pragma unroll
    for (int r = 0; r < 16; r++) acc[r] = 0.f;
#pragma unroll
    for (int c = 0; c < 2; c++)
        acc = __builtin_amdgcn_mfma_f32_32x32x16_bf16(aw[c], bw[c], acc, 0, 0, 0);
    float bb = bps[col];
#pragma unroll
    for (int r = 0; r < 16; r++)
        out[(size_t)(R0 + w*32 + qxmap(r, half))*32 + col] = acc[r] + bb;
}

extern "C" void kernel_launch(void* const* d_in, const int* in_sizes, int n_in,
                              void* d_out, int out_size, void* d_ws, size_t ws_size,
                              hipStream_t stream)
{
    const float* x     = (const float*)d_in[0];
    const float* Wqkv  = (const float*)d_in[1];
    const float* bqkv  = (const float*)d_in[2];
    const float* Wproj = (const float*)d_in[3];
    const float* bproj = (const float*)d_in[4];
    const float* Wsq   = (const float*)d_in[5];
    const float* bsq   = (const float*)d_in[6];
    const float* Wdw   = (const float*)d_in[7];
    const float* bdw   = (const float*)d_in[8];

    const size_t QP = (size_t)BN * NN * DP;   // 3,145,728
    const size_t VB = (size_t)BN * NN * DD;   // 2,752,512
    ushort* qf   = (ushort*)d_ws;
    ushort* kf   = qf + QP;
    ushort* vb   = kf + QP;
    ushort* vf   = vb + VB;
    float* Obuf  = (float*)(vf + QP);
    float* x2    = Obuf + VB;
    float* spool = x2 + 32768;
    float* xw    = spool + 32;
    float* xp    = xw + 8192;
    float* btab  = xp + 8192;
    unsigned* Mg = (unsigned*)(btab + 3969*8);
    float* out   = (float*)d_out;

    qkv_kernel <<<NROWS/128, 256, 0, stream>>>(x, Wqkv, bqkv, qf, kf, vb);
    vtr_kernel <<<dim3(16,32),256, 0, stream>>>(vb, vf);
    x2_kernel  <<<128,        256, 0, stream>>>(x, Wsq, bsq, x2, Mg, qf, kf);
    pool_kernel<<<32,         256, 0, stream>>>(x2, spool);
    lspe_kernel<<<32,         256, 0, stream>>>(x2, spool, Wdw, bdw, xw, xp);
    bias_kernel<<<dim3(63,8), 512, 0, stream>>>(xw, xp, btab, Mg);
    attn_kernel<<<1024,       256, 0, stream>>>(qf, kf, vf, btab, Mg, Obuf);
    proj_kernel<<<NROWS/128,  256, 0, stream>>>(Obuf, Wproj, bproj, out);
}

// Round 7
// 157.348 us; speedup vs baseline: 3.3146x; 1.0246x over previous
//
#include <hip/hip_runtime.h>
#include <math.h>

#define NHEAD 8
#define BATCH 4
#define NN 1024              // H*W
#define MM 21
#define DD 84                // M*hd
#define DP 96                // padded feature dim
#define BN (BATCH*NHEAD)     // 32
#define NROWS (BATCH*NN*MM)  // 86016

typedef __attribute__((ext_vector_type(8))) short bf16x8;
typedef __attribute__((ext_vector_type(16))) float f32x16;

__device__ __forceinline__ unsigned short f2bf(float x) {
    union { float f; unsigned int u; } c; c.f = x;
    unsigned int r = (c.u + 0x7FFFu + ((c.u >> 16) & 1u)) >> 16;
    return (unsigned short)r;
}
__device__ __forceinline__ int qxmap(int r, int half) { return (r & 3) + 8*(r >> 2) + 4*half; }

// Fragment-linear layouts (ushort):
//  Qf/Kf: addr(bh,n,d) = ((bh*32 + n/32)*6 + d/16)*512 + ((d>>3)&1)*256 + (n&31)*8 + (d&7)
//  Vf:    addr(bh,n,d) = (bh*32 + n/32)*3072 + (d/32)*1024 + ((n>>4)&1)*512 + ((n>>3)&1)*256 + (d&31)*8 + (n&7)

// ---------------- Kernel A: qkv projection via MFMA -> Qf,Kf frag-layout (q pre-scaled), v row-major [bh][n][84] ----------------
__global__ __launch_bounds__(256)
void qkv_kernel(const float* __restrict__ x, const float* __restrict__ Wq,
                const float* __restrict__ bq, ushort* __restrict__ qf,
                ushort* __restrict__ kf, ushort* __restrict__ vb)
{
    __shared__ ushort wqs[3072];
    __shared__ float bqs[96];
    __shared__ __align__(16) float xs[128*36];
    __shared__ ushort cs[4*3200];      // per-wave 32x(96+4) repack
    int t = threadIdx.x;
    int w = t >> 6, lane = t & 63, col = lane & 31, half = lane >> 5;
    int R0 = blockIdx.x * 128;

    for (int i = t; i < 3072; i += 256) wqs[i] = f2bf(Wq[i]);
    if (t < 96) bqs[t] = bq[t];
    for (int i = t; i < 4096; i += 256)
        xs[(i >> 5)*36 + (i & 31)] = x[(size_t)R0*32 + i];
    __syncthreads();

    bf16x8 bw[3][2];
#pragma unroll
    for (int f = 0; f < 3; f++)
#pragma unroll
        for (int c = 0; c < 2; c++) {
            union { bf16x8 v; ushort s[8]; } u;
#pragma unroll
            for (int j = 0; j < 8; j++)
                u.s[j] = wqs[(c*16 + half*8 + j)*96 + f*32 + col];
            bw[f][c] = u.v;
        }
    bf16x8 aw[2];
#pragma unroll
    for (int c = 0; c < 2; c++) {
        const float* xr = xs + (w*32 + col)*36 + c*16 + half*8;
        float4 v0 = *(const float4*)(xr);
        float4 v1 = *(const float4*)(xr + 4);
        union { bf16x8 v; ushort s[8]; } u;
        u.s[0]=f2bf(v0.x); u.s[1]=f2bf(v0.y); u.s[2]=f2bf(v0.z); u.s[3]=f2bf(v0.w);
        u.s[4]=f2bf(v1.x); u.s[5]=f2bf(v1.y); u.s[6]=f2bf(v1.z); u.s[7]=f2bf(v1.w);
        aw[c] = u.v;
    }
    f32x16 acc[3];
#pragma unroll
    for (int f = 0; f < 3; f++) {
#pragma unroll
        for (int r = 0; r < 16; r++) acc[f][r] = 0.f;
#pragma unroll
        for (int c = 0; c < 2; c++)
            acc[f] = __builtin_amdgcn_mfma_f32_32x32x16_bf16(aw[c], bw[f][c], acc[f], 0, 0, 0);
    }
    ushort* myc = cs + w*3200;
#pragma unroll
    for (int f = 0; f < 3; f++) {
        float sc = (f == 0) ? 0.03125f : 1.0f;   // fold qk scale into q
        float bb = bqs[f*32 + col];
#pragma unroll
        for (int r = 0; r < 16; r++)
            myc[qxmap(r, half)*100 + f*32 + col] = f2bf((acc[f][r] + bb)*sc);
    }
    __syncthreads();
    int row = lane >> 1, hr = lane & 1;
    int Rr = R0 + w*32 + row;
    int b_ = Rr / 21, m = Rr - b_*21, b = b_ >> 10, n = b_ & 1023;
    size_t fragoff = (size_t)(m >> 2)*512 + ((m >> 1) & 1)*256 + (n & 31)*8 + ((4*m) & 7);
    int nt = n >> 5;
#pragma unroll
    for (int c2 = 0; c2 < 12; c2++) {
        int col4 = hr*48 + c2*4;
        ushort4 v = *(const ushort4*)(myc + row*100 + col4);
        int s = col4 >> 5, hh = (col4 & 31) >> 2;
        if (s == 0)
            *(ushort4*)(qf + (size_t)((b*8 + hh)*32 + nt)*3072 + fragoff) = v;
        else if (s == 1)
            *(ushort4*)(kf + (size_t)((b*8 + hh)*32 + nt)*3072 + fragoff) = v;
        else
            *(ushort4*)(vb + ((size_t)((b*8 + hh)*1024 + n))*DD + m*4) = v;
    }
}

// ---------------- Kernel A2: v [bh][n][84] -> Vf frag layout (d=84 ones, 85..95 zero) ----------------
__global__ __launch_bounds__(256)
void vtr_kernel(const ushort* __restrict__ vb, ushort* __restrict__ vf)
{
    __shared__ ushort ld[64*88];
    int t = threadIdx.x;
    int bh = blockIdx.y, n0 = blockIdx.x * 64;
    for (int i = t; i < 1344; i += 256) {
        int r = i/21, p = i - r*21;
        *(ushort4*)(ld + r*88 + p*4) = *(const ushort4*)(vb + ((size_t)bh*NN + n0 + r)*DD + p*4);
    }
    __syncthreads();
    for (int j = t; j < 1344; j += 256) {
        int d = j >> 4, g = j & 15;
        ushort4 wv;
        wv.x = ld[(g*4+0)*88 + d]; wv.y = ld[(g*4+1)*88 + d];
        wv.z = ld[(g*4+2)*88 + d]; wv.w = ld[(g*4+3)*88 + d];
        int nn = n0 + g*4;
        size_t addr = (size_t)(bh*32 + (nn >> 5))*3072 + (d >> 5)*1024
                    + ((nn >> 4) & 1)*512 + ((nn >> 3) & 1)*256 + (d & 31)*8 + (nn & 7);
        *(ushort4*)(vf + addr) = wv;
    }
    if (t < 192) {
        int r = 84 + t/16, p = t & 15;
        int nn = n0 + p*4;
        ushort e = (r == 84) ? (ushort)0x3F80 : (ushort)0;
        size_t addr = (size_t)(bh*32 + (nn >> 5))*3072 + 2*1024
                    + ((nn >> 4) & 1)*512 + ((nn >> 3) & 1)*256 + (r & 31)*8 + (nn & 7);
        *(ushort4*)(vf + addr) = make_ushort4(e, e, e, e);
    }
}

// ---------------- Kernel B: x2 = x . W_sq + b_sq (wave-per-row, coalesced) ; init Mg ; zero q/k frag pads ----------------
// grid 256 x 256 threads: wave wid handles rows 4*wid .. 4*wid+3 (row = b*1024+n).
__global__ __launch_bounds__(256)
void x2_kernel(const float* __restrict__ x, const float* __restrict__ Wsq,
               const float* __restrict__ bsq, float* __restrict__ x2,
               unsigned* __restrict__ Mg, ushort* __restrict__ qf,
               ushort* __restrict__ kf)
{
    __shared__ __align__(16) float ws[84];
    int t = threadIdx.x;
    if (t < 84) ws[t] = Wsq[t];
    if (blockIdx.x == 0 && t < 8) Mg[t] = 0u;
    __syncthreads();
    int w = t >> 6, l = t & 63;
    int wid = blockIdx.x*4 + w;
    float bs0 = bsq[0];
    int dd = l & 3;
    for (int rr = 0; rr < 4; rr++) {
        int row = wid*4 + rr;                 // b*1024 + n
        int b = row >> 10, n = row & 1023;
        const float* xr = x + (size_t)row*672;
        float acc = 0.f;
#pragma unroll
        for (int p = 0; p < 11; p++) {
            int idx = p*64 + l;
            int m = idx >> 5;
            if (m < 21) acc += xr[idx] * ws[m*4 + dd];
        }
        acc += __shfl_xor(acc, 32);
        acc += __shfl_xor(acc, 1);
        acc += __shfl_xor(acc, 2);
        if ((l & 3) == 0 && l < 32) {
            int h = l >> 2;
            x2[(size_t)(b*8 + h)*1024 + n] = acc + bs0;
        }
        if (l < 48) {
            int h = l / 6, piece = l % 6;
            size_t base = (size_t)((b*8 + h)*32 + (n >> 5))*3072 + 5*512 + (n & 31)*8;
            int pm = piece % 3;
            size_t off = (pm == 0) ? 4 : (pm == 1) ? 256 : 260;
            ushort* dst = (piece < 3) ? qf : kf;
            *(ushort4*)(dst + base + off) = make_ushort4(0,0,0,0);
        }
    }
}

// ---------------- Kernel C: per-(b,h) avg+max pool ----------------
__global__ __launch_bounds__(256)
void pool_kernel(const float* __restrict__ x2, float* __restrict__ spool)
{
    int bh = blockIdx.x;
    int t = threadIdx.x;
    const float* p = x2 + (size_t)bh*NN;
    float s = 0.f, mx = -INFINITY;
    for (int i = t; i < NN; i += 256) { float v = p[i]; s += v; mx = fmaxf(mx, v); }
#pragma unroll
    for (int off = 1; off < 64; off <<= 1) {
        s  += __shfl_xor(s, off);
        mx  = fmaxf(mx, __shfl_xor(mx, off));
    }
    __shared__ float rs[4], rm[4];
    int w = t >> 6;
    if ((t & 63) == 0) { rs[w] = s; rm[w] = mx; }
    __syncthreads();
    if (t == 0) {
        float ss = rs[0]+rs[1]+rs[2]+rs[3];
        float mm = fmaxf(fmaxf(rm[0],rm[1]), fmaxf(rm[2],rm[3]));
        spool[bh] = ss * (1.f/1024.f) + mm;
    }
}

// ---------------- Kernel D: depthwise conv + pooled, batch-mean -> xw, xp ----------------
__global__ __launch_bounds__(256)
void lspe_kernel(const float* __restrict__ x2, const float* __restrict__ spool,
                 const float* __restrict__ Wdw, const float* __restrict__ bdw,
                 float* __restrict__ xw, float* __restrict__ xp)
{
    int i = blockIdx.x*256 + threadIdx.x;
    int h = i >> 10;
    int n = i & 1023;
    int y = n >> 5, xx = n & 31;
    int g0 = h >> 1;
    float accW = 0.f, accP = 0.f;
    for (int b = 0; b < 4; b++) {
        float sp = spool[b*8 + h];
        float c0 = bdw[h], c1 = bdw[8 + h];
        const float* a0 = x2 + (size_t)(b*8 + g0)*NN;
        const float* a1 = x2 + (size_t)(b*8 + 4 + g0)*NN;
#pragma unroll
        for (int ky = 0; ky < 3; ky++) {
            int yy = y + ky - 1;
            if (yy < 0 || yy > 31) continue;
#pragma unroll
            for (int kx = 0; kx < 3; kx++) {
                int xc = xx + kx - 1;
                if (xc < 0 || xc > 31) continue;
                c0 += a0[yy*32 + xc] * Wdw[h*9 + ky*3 + kx];
                c1 += a1[yy*32 + xc] * Wdw[(8+h)*9 + ky*3 + kx];
            }
        }
        accW += c0 + sp;
        accP += c1 + sp;
    }
    xw[i] = 0.25f * accW;
    xp[i] = 0.25f * accP;
}

// ---------------- Kernel E: correlation -> 63x63 bias table + per-head global max ----------------
// grid (63, 8) = (oy, h); 512 threads: t = aw*64 + ox, aw in [0,8) splits the a-sum.
__global__ __launch_bounds__(512)
void bias_kernel(const float* __restrict__ xw, const float* __restrict__ xp,
                 float* __restrict__ btab, unsigned* __restrict__ Mg)
{
    __shared__ float sxw[1024], sxp[1024];
    __shared__ float part[8][64];
    int h = blockIdx.y, oy = blockIdx.x;
    int t = threadIdx.x;
    for (int i = t; i < 1024; i += 512) { sxw[i] = xw[h*1024+i]; sxp[i] = xp[h*1024+i]; }
    __syncthreads();
    int ox = t & 63;           // 63 valid outputs; ox==63 idle
    int aw = t >> 6;           // 0..7
    int alo = max(0, oy-31), ahi = min(31, oy);
    int clo = max(0, ox-31), chi = min(31, ox);
    int cnt = chi - clo + 1;   // 1..32 (ox<63)
    float acc0 = 0.f, acc1 = 0.f;
    if (ox < 63) {
        for (int a = alo + aw; a <= ahi; a += 8) {
            const float* prow = sxp + a*32 + clo;
            const float* wrow = sxw + (oy - a)*32 + (ox - clo);
            int k = 0;
            for (; k + 1 < cnt; k += 2) {
                acc0 += prow[k]   * wrow[-k];
                acc1 += prow[k+1] * wrow[-k-1];
            }
            if (k < cnt) acc0 += prow[k] * wrow[-k];
        }
    }
    part[aw][ox] = acc0 + acc1;
    __syncthreads();
    if (t < 64) {
        float acc = 0.f;
#pragma unroll
        for (int j = 0; j < 8; j++) acc += part[j][t];
        unsigned key = 0u;
        if (t < 63) {
            btab[h*3969 + oy*63 + t] = acc;
            unsigned u = __float_as_uint(acc);
            key = (u & 0x80000000u) ? ~u : (u | 0x80000000u);
        }
#pragma unroll
        for (int off = 1; off < 64; off <<= 1) {
            unsigned o = __shfl_xor(key, off);
            key = key > o ? key : o;
        }
        if (t == 0) atomicMax(Mg + h, key);
    }
}

// ---------------- Kernel F: barrier-free MFMA flash attention, coalesced frag-linear loads ----------------
// grid 1024: bh = bid&31 (XCD-local), qt = bid>>5; 4 independent waves, wave w owns kt = 4j+w.
__global__ __launch_bounds__(256, 4)
void attn_kernel(const ushort* __restrict__ qg, const ushort* __restrict__ kg,
                 const ushort* __restrict__ vg, const float* __restrict__ btg,
                 const unsigned* __restrict__ Mg, float* __restrict__ Obuf)
{
    __shared__ float btabS[2016];        // 32 table rows for this q y-row
    __shared__ float red[2][64*52];
    __shared__ float lred[32];

    int t = threadIdx.x;
    int bid = blockIdx.x;
    int bh = bid & 31, qt = bid >> 5;
    int h = bh & 7, b = bh >> 3;
    int q0 = qt * 32;

    float Mh;
    { unsigned k = Mg[h]; unsigned u = (k & 0x80000000u) ? (k ^ 0x80000000u) : ~k; Mh = __uint_as_float(u); }
    const float* bsrc = btg + h*3969 + qt*63;      // rows yq .. yq+31
    for (int i = t; i < 2016; i += 256) btabS[i] = bsrc[i] - Mh;
    __syncthreads();

    int w = t >> 6, lane = t & 63, col = lane & 31, half = lane >> 5;
    int lofs = half*256 + col*8;

    bf16x8 bq6[6];
    const ushort* qbase = qg + (size_t)(bh*32 + qt)*3072 + lofs;
#pragma unroll
    for (int s = 0; s < 6; s++) bq6[s] = *(const bf16x8*)(qbase + s*512);

    f32x16 of[3];
#pragma unroll
    for (int f = 0; f < 3; f++)
#pragma unroll
        for (int r = 0; r < 16; r++) of[f][r] = 0.f;

    int kx_[16];
#pragma unroll
    for (int r = 0; r < 16; r++) kx_[r] = qxmap(r, half);

    const ushort* kall = kg + (size_t)bh*32*3072 + lofs;
    const ushort* vall = vg + (size_t)bh*32*3072 + lofs;

    bf16x8 akc[6];
    {
        const ushort* kr = kall + (size_t)w*3072;
#pragma unroll
        for (int s = 0; s < 6; s++) akc[s] = *(const bf16x8*)(kr + s*512);
    }

    for (int j = 0; j < 8; j++) {
        int kt = 4*j + w;
        const ushort* vr = vall + (size_t)kt*3072;
        bf16x8 vfr[3][2];
#pragma unroll
        for (int f = 0; f < 3; f++)
#pragma unroll
            for (int c = 0; c < 2; c++)
                vfr[f][c] = *(const bf16x8*)(vr + f*1024 + c*512);

        f32x16 st;
#pragma unroll
        for (int r = 0; r < 16; r++) st[r] = 0.f;
#pragma unroll
        for (int s = 0; s < 6; s++)
            st = __builtin_amdgcn_mfma_f32_32x32x16_bf16(akc[s], bq6[s], st, 0, 0, 0);

        bf16x8 akn[6];
        if (j < 7) {
            const ushort* kr = kall + (size_t)(kt + 4)*3072;
#pragma unroll
            for (int s = 0; s < 6; s++) akn[s] = *(const bf16x8*)(kr + s*512);
        }

        const float* bp = btabS + (31 - kt)*63 + col + 31;
        unsigned P[8];
#pragma unroll
        for (int g = 0; g < 8; g++) {
            float p0 = __expf(st[2*g]   + bp[-kx_[2*g]]);
            float p1 = __expf(st[2*g+1] + bp[-kx_[2*g+1]]);
            unsigned u0 = __float_as_uint(p0) + 0x8000u;
            unsigned u1 = __float_as_uint(p1) + 0x8000u;
            P[g] = (u1 & 0xFFFF0000u) | (u0 >> 16);
        }
        unsigned XP[8];
#pragma unroll
        for (int g = 0; g < 8; g++) XP[g] = (unsigned)__shfl_xor((int)P[g], 32);

        union { bf16x8 v; unsigned u[4]; } f0, f1;
        f0.u[0] = half ? XP[2] : P[0];
        f0.u[1] = half ? XP[3] : P[1];
        f0.u[2] = half ? P[2]  : XP[0];
        f0.u[3] = half ? P[3]  : XP[1];
        f1.u[0] = half ? XP[6] : P[4];
        f1.u[1] = half ? XP[7] : P[5];
        f1.u[2] = half ? P[6]  : XP[4];
        f1.u[3] = half ? P[7]  : XP[5];

#pragma unroll
        for (int f = 0; f < 3; f++) {
            of[f] = __builtin_amdgcn_mfma_f32_32x32x16_bf16(f0.v, vfr[f][0], of[f], 0, 0, 0);
            of[f] = __builtin_amdgcn_mfma_f32_32x32x16_bf16(f1.v, vfr[f][1], of[f], 0, 0, 0);
        }
        if (j < 7) {
#pragma unroll
            for (int s = 0; s < 6; s++) akc[s] = akn[s];
        }
    }

    // ---- 4-way O reduction (tree) + epilogue ----
    __syncthreads();
    if (w == 1 || w == 3) {
        float* dst = red[w >> 1] + lane*52;
#pragma unroll
        for (int f = 0; f < 3; f++)
#pragma unroll
            for (int r = 0; r < 16; r++) dst[f*16 + r] = of[f][r];
    }
    __syncthreads();
    if (w == 0 || w == 2) {
        const float* src = red[w >> 1] + lane*52;
#pragma unroll
        for (int f = 0; f < 3; f++)
#pragma unroll
            for (int r = 0; r < 16; r++) of[f][r] += src[f*16 + r];
    }
    __syncthreads();
    if (w == 2) {
        float* dst = red[0] + lane*52;
#pragma unroll
        for (int f = 0; f < 3; f++)
#pragma unroll
            for (int r = 0; r < 16; r++) dst[f*16 + r] = of[f][r];
    }
    __syncthreads();
    if (w == 0) {
        const float* src = red[0] + lane*52;
#pragma unroll
        for (int f = 0; f < 3; f++)
#pragma unroll
            for (int r = 0; r < 16; r++) of[f][r] += src[f*16 + r];
        if (col == 20) {
#pragma unroll
            for (int r = 0; r < 16; r++) lred[qxmap(r, half)] = of[2][r];
        }
    }
    __syncthreads();
    if (w == 0) {
        float linv[16];
#pragma unroll
        for (int r = 0; r < 16; r++) linv[r] = 1.0f / lred[qxmap(r, half)];
#pragma unroll
        for (int f = 0; f < 3; f++) {
            int d = f*32 + col;
            if (d < DD) {
                int m = d >> 2, dd2 = d & 3;
#pragma unroll
                for (int r = 0; r < 16; r++) {
                    int q = qxmap(r, half);
                    size_t R = ((size_t)(b*NN + q0 + q))*21 + m;
                    Obuf[R*32 + h*4 + dd2] = of[f][r] * linv[r];
                }
            }
        }
    }
}

// ---------------- Kernel G: output projection via MFMA (LDS-staged activations) ----------------
__global__ __launch_bounds__(256)
void proj_kernel(const float* __restrict__ Obuf, const float* __restrict__ Wp,
                 const float* __restrict__ bp, float* __restrict__ out)
{
    __shared__ ushort wps[1024];
    __shared__ float bps[32];
    __shared__ __align__(16) float os[128*36];
    int t = threadIdx.x;
    int w = t >> 6, lane = t & 63, col = lane & 31, half = lane >> 5;
    int R0 = blockIdx.x * 128;
    for (int i = t; i < 1024; i += 256) wps[i] = f2bf(Wp[i]);
    if (t < 32) bps[t] = bp[t];
    for (int i = t; i < 4096; i += 256)
        os[(i >> 5)*36 + (i & 31)] = Obuf[(size_t)R0*32 + i];
    __syncthreads();

    bf16x8 bw[2];
#pragma unroll
    for (int c = 0; c < 2; c++) {
        union { bf16x8 v; ushort s[8]; } u;
#pragma unroll
        for (int j = 0; j < 8; j++)
            u.s[j] = wps[(c*16 + half*8 + j)*32 + col];
        bw[c] = u.v;
    }
    bf16x8 aw[2];
#pragma unroll
    for (int c = 0; c < 2; c++) {
        const float* orr = os + (w*32 + col)*36 + c*16 + half*8;
        float4 v0 = *(const float4*)(orr);
        float4 v1 = *(const float4*)(orr + 4);
        union { bf16x8 v; ushort s[8]; } u;
        u.s[0]=f2bf(v0.x); u.s[1]=f2bf(v0.y); u.s[2]=f2bf(v0.z); u.s[3]=f2bf(v0.w);
        u.s[4]=f2bf(v1.x); u.s[5]=f2bf(v1.y); u.s[6]=f2bf(v1.z); u.s[7]=f2bf(v1.w);
        aw[c] = u.v;
    }
    f32x16 acc;
#pragma unroll
    for (int r = 0; r < 16; r++) acc[r] = 0.f;
#pragma unroll
    for (int c = 0; c < 2; c++)
        acc = __builtin_amdgcn_mfma_f32_32x32x16_bf16(aw[c], bw[c], acc, 0, 0, 0);
    float bb = bps[col];
#pragma unroll
    for (int r = 0; r < 16; r++)
        out[(size_t)(R0 + w*32 + qxmap(r, half))*32 + col] = acc[r] + bb;
}

extern "C" void kernel_launch(void* const* d_in, const int* in_sizes, int n_in,
                              void* d_out, int out_size, void* d_ws, size_t ws_size,
                              hipStream_t stream)
{
    const float* x     = (const float*)d_in[0];
    const float* Wqkv  = (const float*)d_in[1];
    const float* bqkv  = (const float*)d_in[2];
    const float* Wproj = (const float*)d_in[3];
    const float* bproj = (const float*)d_in[4];
    const float* Wsq   = (const float*)d_in[5];
    const float* bsq   = (const float*)d_in[6];
    const float* Wdw   = (const float*)d_in[7];
    const float* bdw   = (const float*)d_in[8];

    const size_t QP = (size_t)BN * NN * DP;   // 3,145,728
    const size_t VB = (size_t)BN * NN * DD;   // 2,752,512
    ushort* qf   = (ushort*)d_ws;
    ushort* kf   = qf + QP;
    ushort* vb   = kf + QP;
    ushort* vf   = vb + VB;
    float* Obuf  = (float*)(vf + QP);
    float* x2    = Obuf + VB;
    float* spool = x2 + 32768;
    float* xw    = spool + 32;
    float* xp    = xw + 8192;
    float* btab  = xp + 8192;
    unsigned* Mg = (unsigned*)(btab + 3969*8);
    float* out   = (float*)d_out;

    qkv_kernel <<<NROWS/128, 256, 0, stream>>>(x, Wqkv, bqkv, qf, kf, vb);
    vtr_kernel <<<dim3(16,32),256, 0, stream>>>(vb, vf);
    x2_kernel  <<<256,        256, 0, stream>>>(x, Wsq, bsq, x2, Mg, qf, kf);
    pool_kernel<<<32,         256, 0, stream>>>(x2, spool);
    lspe_kernel<<<32,         256, 0, stream>>>(x2, spool, Wdw, bdw, xw, xp);
    bias_kernel<<<dim3(63,8), 512, 0, stream>>>(xw, xp, btab, Mg);
    attn_kernel<<<1024,       256, 0, stream>>>(qf, kf, vf, btab, Mg, Obuf);
    proj_kernel<<<NROWS/128,  256, 0, stream>>>(Obuf, Wproj, bproj, out);
}

// Round 8
// 153.158 us; speedup vs baseline: 3.4052x; 1.0274x over previous
//
#include <hip/hip_runtime.h>
#include <math.h>

#define NHEAD 8
#define BATCH 4
#define NN 1024              // H*W
#define MM 21
#define DD 84                // M*hd
#define DP 96                // padded feature dim
#define BN (BATCH*NHEAD)     // 32
#define NROWS (BATCH*NN*MM)  // 86016

typedef __attribute__((ext_vector_type(8))) short bf16x8;
typedef __attribute__((ext_vector_type(16))) float f32x16;

__device__ __forceinline__ unsigned short f2bf(float x) {
    union { float f; unsigned int u; } c; c.f = x;
    unsigned int r = (c.u + 0x7FFFu + ((c.u >> 16) & 1u)) >> 16;
    return (unsigned short)r;
}
__device__ __forceinline__ int qxmap(int r, int half) { return (r & 3) + 8*(r >> 2) + 4*half; }

// Fragment-linear layouts (ushort):
//  Qf/Kf: addr(bh,n,d) = ((bh*32 + n/32)*6 + d/16)*512 + ((d>>3)&1)*256 + (n&31)*8 + (d&7)
//  Vf:    addr(bh,n,d) = (bh*32 + n/32)*3072 + (d/32)*1024 + ((n>>4)&1)*512 + ((n>>3)&1)*256 + (d&31)*8 + (n&7)

// ================ L1: fused qkv-projection (blocks 0..671) + x2/Mg/pads (blocks 672..735) ================
__global__ __launch_bounds__(256)
void l1_kernel(const float* __restrict__ x, const float* __restrict__ Wq,
               const float* __restrict__ bq, const float* __restrict__ Wsq,
               const float* __restrict__ bsq, ushort* __restrict__ qf,
               ushort* __restrict__ kf, ushort* __restrict__ vb,
               float* __restrict__ x2, unsigned* __restrict__ Mg)
{
    int t = threadIdx.x;
    int w = t >> 6, lane = t & 63, col = lane & 31, half = lane >> 5;

    if (blockIdx.x < 672) {
        // ---------------- qkv role ----------------
        __shared__ ushort wqs[3072];
        __shared__ float bqs[96];
        __shared__ __align__(16) float xs[128*36];
        __shared__ ushort cs[4*3200];      // per-wave 32x(96+4) repack
        int R0 = blockIdx.x * 128;

        for (int i = t; i < 3072; i += 256) wqs[i] = f2bf(Wq[i]);
        if (t < 96) bqs[t] = bq[t];
        for (int i = t; i < 4096; i += 256)
            xs[(i >> 5)*36 + (i & 31)] = x[(size_t)R0*32 + i];
        __syncthreads();

        bf16x8 bw[3][2];
#pragma unroll
        for (int f = 0; f < 3; f++)
#pragma unroll
            for (int c = 0; c < 2; c++) {
                union { bf16x8 v; ushort s[8]; } u;
#pragma unroll
                for (int j = 0; j < 8; j++)
                    u.s[j] = wqs[(c*16 + half*8 + j)*96 + f*32 + col];
                bw[f][c] = u.v;
            }
        bf16x8 aw[2];
#pragma unroll
        for (int c = 0; c < 2; c++) {
            const float* xr = xs + (w*32 + col)*36 + c*16 + half*8;
            float4 v0 = *(const float4*)(xr);
            float4 v1 = *(const float4*)(xr + 4);
            union { bf16x8 v; ushort s[8]; } u;
            u.s[0]=f2bf(v0.x); u.s[1]=f2bf(v0.y); u.s[2]=f2bf(v0.z); u.s[3]=f2bf(v0.w);
            u.s[4]=f2bf(v1.x); u.s[5]=f2bf(v1.y); u.s[6]=f2bf(v1.z); u.s[7]=f2bf(v1.w);
            aw[c] = u.v;
        }
        f32x16 acc[3];
#pragma unroll
        for (int f = 0; f < 3; f++) {
#pragma unroll
            for (int r = 0; r < 16; r++) acc[f][r] = 0.f;
#pragma unroll
            for (int c = 0; c < 2; c++)
                acc[f] = __builtin_amdgcn_mfma_f32_32x32x16_bf16(aw[c], bw[f][c], acc[f], 0, 0, 0);
        }
        ushort* myc = cs + w*3200;
#pragma unroll
        for (int f = 0; f < 3; f++) {
            float sc = (f == 0) ? 0.03125f : 1.0f;   // fold qk scale into q
            float bb = bqs[f*32 + col];
#pragma unroll
            for (int r = 0; r < 16; r++)
                myc[qxmap(r, half)*100 + f*32 + col] = f2bf((acc[f][r] + bb)*sc);
        }
        __syncthreads();
        int row = lane >> 1, hr = lane & 1;
        int Rr = R0 + w*32 + row;
        int b_ = Rr / 21, m = Rr - b_*21, b = b_ >> 10, n = b_ & 1023;
        size_t fragoff = (size_t)(m >> 2)*512 + ((m >> 1) & 1)*256 + (n & 31)*8 + ((4*m) & 7);
        int nt = n >> 5;
#pragma unroll
        for (int c2 = 0; c2 < 12; c2++) {
            int col4 = hr*48 + c2*4;
            ushort4 v = *(const ushort4*)(myc + row*100 + col4);
            int s = col4 >> 5, hh = (col4 & 31) >> 2;
            if (s == 0)
                *(ushort4*)(qf + (size_t)((b*8 + hh)*32 + nt)*3072 + fragoff) = v;
            else if (s == 1)
                *(ushort4*)(kf + (size_t)((b*8 + hh)*32 + nt)*3072 + fragoff) = v;
            else
                *(ushort4*)(vb + ((size_t)((b*8 + hh)*1024 + n))*DD + m*4) = v;
        }
    } else {
        // ---------------- x2 role: 64 blocks, wave-per-row ----------------
        __shared__ __align__(16) float ws[84];
        int bx = blockIdx.x - 672;
        if (t < 84) ws[t] = Wsq[t];
        if (bx == 0 && t < 8) Mg[t] = 0u;
        __syncthreads();
        int wid = bx*4 + w;
        float bs0 = bsq[0];
        int dd = lane & 3;
        for (int rr = 0; rr < 16; rr++) {
            int rowi = wid*16 + rr;              // b*1024 + n
            int b = rowi >> 10, n = rowi & 1023;
            const float* xr = x + (size_t)rowi*672;
            float acc = 0.f;
#pragma unroll
            for (int p = 0; p < 11; p++) {
                int idx = p*64 + lane;
                int m = idx >> 5;
                if (m < 21) acc += xr[idx] * ws[m*4 + dd];
            }
            acc += __shfl_xor(acc, 32);
            acc += __shfl_xor(acc, 1);
            acc += __shfl_xor(acc, 2);
            if ((lane & 3) == 0 && lane < 32) {
                int h = lane >> 2;
                x2[(size_t)(b*8 + h)*1024 + n] = acc + bs0;
            }
            if (lane < 48) {
                int h = lane / 6, piece = lane % 6;
                size_t base = (size_t)((b*8 + h)*32 + (n >> 5))*3072 + 5*512 + (n & 31)*8;
                int pm = piece % 3;
                size_t off = (pm == 0) ? 4 : (pm == 1) ? 256 : 260;
                ushort* dst = (piece < 3) ? qf : kf;
                *(ushort4*)(dst + base + off) = make_ushort4(0,0,0,0);
            }
        }
    }
}

// ================ L2: fused vtr (blocks 0..511) + lspe-with-inline-pool (blocks 512..543) ================
__global__ __launch_bounds__(256)
void l2_kernel(const ushort* __restrict__ vb, ushort* __restrict__ vf,
               const float* __restrict__ x2, const float* __restrict__ Wdw,
               const float* __restrict__ bdw, float* __restrict__ xw,
               float* __restrict__ xp)
{
    int t = threadIdx.x;
    if (blockIdx.x < 512) {
        // ---------------- vtr role ----------------
        __shared__ ushort ld[64*88];
        int bh = blockIdx.x >> 4, n0 = (blockIdx.x & 15) * 64;
        for (int i = t; i < 1344; i += 256) {
            int r = i/21, p = i - r*21;
            *(ushort4*)(ld + r*88 + p*4) = *(const ushort4*)(vb + ((size_t)bh*NN + n0 + r)*DD + p*4);
        }
        __syncthreads();
        for (int j = t; j < 1344; j += 256) {
            int d = j >> 4, g = j & 15;
            ushort4 wv;
            wv.x = ld[(g*4+0)*88 + d]; wv.y = ld[(g*4+1)*88 + d];
            wv.z = ld[(g*4+2)*88 + d]; wv.w = ld[(g*4+3)*88 + d];
            int nn = n0 + g*4;
            size_t addr = (size_t)(bh*32 + (nn >> 5))*3072 + (d >> 5)*1024
                        + ((nn >> 4) & 1)*512 + ((nn >> 3) & 1)*256 + (d & 31)*8 + (nn & 7);
            *(ushort4*)(vf + addr) = wv;
        }
        if (t < 192) {
            int r = 84 + t/16, p = t & 15;
            int nn = n0 + p*4;
            ushort e = (r == 84) ? (ushort)0x3F80 : (ushort)0;
            size_t addr = (size_t)(bh*32 + (nn >> 5))*3072 + 2*1024
                        + ((nn >> 4) & 1)*512 + ((nn >> 3) & 1)*256 + (r & 31)*8 + (nn & 7);
            *(ushort4*)(vf + addr) = make_ushort4(e, e, e, e);
        }
    } else {
        // ---------------- lspe role with inline pool: 32 blocks, i = idx*256+t over h*1024+n ----------------
        __shared__ float sp[4];
        int idx = blockIdx.x - 512;
        int w = t >> 6, lane = t & 63;
        int i = idx*256 + t;
        int h = i >> 10;
        // wave w computes pool for (b=w, h): avg+max over x2[(w*8+h)*1024 + :]
        {
            const float* p = x2 + (size_t)(w*8 + h)*NN;
            float s = 0.f, mx = -INFINITY;
            for (int k = lane; k < NN; k += 64) { float v = p[k]; s += v; mx = fmaxf(mx, v); }
#pragma unroll
            for (int off = 1; off < 64; off <<= 1) {
                s  += __shfl_xor(s, off);
                mx  = fmaxf(mx, __shfl_xor(mx, off));
            }
            if (lane == 0) sp[w] = s * (1.f/1024.f) + mx;
        }
        __syncthreads();
        int n = i & 1023;
        int y = n >> 5, xx = n & 31;
        int g0 = h >> 1;
        float accW = 0.f, accP = 0.f;
        for (int b = 0; b < 4; b++) {
            float spl = sp[b];
            float c0 = bdw[h], c1 = bdw[8 + h];
            const float* a0 = x2 + (size_t)(b*8 + g0)*NN;
            const float* a1 = x2 + (size_t)(b*8 + 4 + g0)*NN;
#pragma unroll
            for (int ky = 0; ky < 3; ky++) {
                int yy = y + ky - 1;
                if (yy < 0 || yy > 31) continue;
#pragma unroll
                for (int kx = 0; kx < 3; kx++) {
                    int xc = xx + kx - 1;
                    if (xc < 0 || xc > 31) continue;
                    c0 += a0[yy*32 + xc] * Wdw[h*9 + ky*3 + kx];
                    c1 += a1[yy*32 + xc] * Wdw[(8+h)*9 + ky*3 + kx];
                }
            }
            accW += c0 + spl;
            accP += c1 + spl;
        }
        xw[i] = 0.25f * accW;
        xp[i] = 0.25f * accP;
    }
}

// ================ L3: correlation -> 63x63 bias table + per-head global max ================
// grid (63, 8) = (oy, h); 512 threads: t = aw*64 + ox, aw in [0,8) splits the a-sum.
__global__ __launch_bounds__(512)
void bias_kernel(const float* __restrict__ xw, const float* __restrict__ xp,
                 float* __restrict__ btab, unsigned* __restrict__ Mg)
{
    __shared__ float sxw[1024], sxp[1024];
    __shared__ float part[8][64];
    int h = blockIdx.y, oy = blockIdx.x;
    int t = threadIdx.x;
    for (int i = t; i < 1024; i += 512) { sxw[i] = xw[h*1024+i]; sxp[i] = xp[h*1024+i]; }
    __syncthreads();
    int ox = t & 63;           // 63 valid outputs; ox==63 idle
    int aw = t >> 6;           // 0..7
    int alo = max(0, oy-31), ahi = min(31, oy);
    int clo = max(0, ox-31), chi = min(31, ox);
    int cnt = chi - clo + 1;   // 1..32 (ox<63)
    float acc0 = 0.f, acc1 = 0.f;
    if (ox < 63) {
        for (int a = alo + aw; a <= ahi; a += 8) {
            const float* prow = sxp + a*32 + clo;
            const float* wrow = sxw + (oy - a)*32 + (ox - clo);
            int k = 0;
            for (; k + 1 < cnt; k += 2) {
                acc0 += prow[k]   * wrow[-k];
                acc1 += prow[k+1] * wrow[-k-1];
            }
            if (k < cnt) acc0 += prow[k] * wrow[-k];
        }
    }
    part[aw][ox] = acc0 + acc1;
    __syncthreads();
    if (t < 64) {
        float acc = 0.f;
#pragma unroll
        for (int j = 0; j < 8; j++) acc += part[j][t];
        unsigned key = 0u;
        if (t < 63) {
            btab[h*3969 + oy*63 + t] = acc;
            unsigned u = __float_as_uint(acc);
            key = (u & 0x80000000u) ? ~u : (u | 0x80000000u);
        }
#pragma unroll
        for (int off = 1; off < 64; off <<= 1) {
            unsigned o = __shfl_xor(key, off);
            key = key > o ? key : o;
        }
        if (t == 0) atomicMax(Mg + h, key);
    }
}

// ================ L4: barrier-free MFMA flash attention ================
// grid 1024: bh = bid&31 (XCD-local), qt = bid>>5; 4 independent waves, wave w owns kt = 4j+w.
__global__ __launch_bounds__(256, 4)
void attn_kernel(const ushort* __restrict__ qg, const ushort* __restrict__ kg,
                 const ushort* __restrict__ vg, const float* __restrict__ btg,
                 const unsigned* __restrict__ Mg, float* __restrict__ Obuf)
{
    __shared__ float btabS[2016];        // 32 table rows for this q y-row
    __shared__ float red[2][64*52];
    __shared__ float lred[32];

    int t = threadIdx.x;
    int bid = blockIdx.x;
    int bh = bid & 31, qt = bid >> 5;
    int h = bh & 7, b = bh >> 3;
    int q0 = qt * 32;

    float Mh;
    { unsigned k = Mg[h]; unsigned u = (k & 0x80000000u) ? (k ^ 0x80000000u) : ~k; Mh = __uint_as_float(u); }
    const float* bsrc = btg + h*3969 + qt*63;      // rows yq .. yq+31
    for (int i = t; i < 2016; i += 256) btabS[i] = bsrc[i] - Mh;
    __syncthreads();

    int w = t >> 6, lane = t & 63, col = lane & 31, half = lane >> 5;
    int lofs = half*256 + col*8;

    bf16x8 bq6[6];
    const ushort* qbase = qg + (size_t)(bh*32 + qt)*3072 + lofs;
#pragma unroll
    for (int s = 0; s < 6; s++) bq6[s] = *(const bf16x8*)(qbase + s*512);

    f32x16 of[3];
#pragma unroll
    for (int f = 0; f < 3; f++)
#pragma unroll
        for (int r = 0; r < 16; r++) of[f][r] = 0.f;

    int kx_[16];
#pragma unroll
    for (int r = 0; r < 16; r++) kx_[r] = qxmap(r, half);

    const ushort* kall = kg + (size_t)bh*32*3072 + lofs;
    const ushort* vall = vg + (size_t)bh*32*3072 + lofs;

    bf16x8 akc[6];
    {
        const ushort* kr = kall + (size_t)w*3072;
#pragma unroll
        for (int s = 0; s < 6; s++) akc[s] = *(const bf16x8*)(kr + s*512);
    }

    for (int j = 0; j < 8; j++) {
        int kt = 4*j + w;
        const ushort* vr = vall + (size_t)kt*3072;
        bf16x8 vfr[3][2];
#pragma unroll
        for (int f = 0; f < 3; f++)
#pragma unroll
            for (int c = 0; c < 2; c++)
                vfr[f][c] = *(const bf16x8*)(vr + f*1024 + c*512);

        f32x16 st;
#pragma unroll
        for (int r = 0; r < 16; r++) st[r] = 0.f;
#pragma unroll
        for (int s = 0; s < 6; s++)
            st = __builtin_amdgcn_mfma_f32_32x32x16_bf16(akc[s], bq6[s], st, 0, 0, 0);

        bf16x8 akn[6];
        if (j < 7) {
            const ushort* kr = kall + (size_t)(kt + 4)*3072;
#pragma unroll
            for (int s = 0; s < 6; s++) akn[s] = *(const bf16x8*)(kr + s*512);
        }

        const float* bp = btabS + (31 - kt)*63 + col + 31;
        unsigned P[8];
#pragma unroll
        for (int g = 0; g < 8; g++) {
            float p0 = __expf(st[2*g]   + bp[-kx_[2*g]]);
            float p1 = __expf(st[2*g+1] + bp[-kx_[2*g+1]]);
            unsigned u0 = __float_as_uint(p0) + 0x8000u;
            unsigned u1 = __float_as_uint(p1) + 0x8000u;
            P[g] = (u1 & 0xFFFF0000u) | (u0 >> 16);
        }
        unsigned XP[8];
#pragma unroll
        for (int g = 0; g < 8; g++) XP[g] = (unsigned)__shfl_xor((int)P[g], 32);

        union { bf16x8 v; unsigned u[4]; } f0, f1;
        f0.u[0] = half ? XP[2] : P[0];
        f0.u[1] = half ? XP[3] : P[1];
        f0.u[2] = half ? P[2]  : XP[0];
        f0.u[3] = half ? P[3]  : XP[1];
        f1.u[0] = half ? XP[6] : P[4];
        f1.u[1] = half ? XP[7] : P[5];
        f1.u[2] = half ? P[6]  : XP[4];
        f1.u[3] = half ? P[7]  : XP[5];

#pragma unroll
        for (int f = 0; f < 3; f++) {
            of[f] = __builtin_amdgcn_mfma_f32_32x32x16_bf16(f0.v, vfr[f][0], of[f], 0, 0, 0);
            of[f] = __builtin_amdgcn_mfma_f32_32x32x16_bf16(f1.v, vfr[f][1], of[f], 0, 0, 0);
        }
        if (j < 7) {
#pragma unroll
            for (int s = 0; s < 6; s++) akc[s] = akn[s];
        }
    }

    // ---- 4-way O reduction (tree) + epilogue ----
    __syncthreads();
    if (w == 1 || w == 3) {
        float* dst = red[w >> 1] + lane*52;
#pragma unroll
        for (int f = 0; f < 3; f++)
#pragma unroll
            for (int r = 0; r < 16; r++) dst[f*16 + r] = of[f][r];
    }
    __syncthreads();
    if (w == 0 || w == 2) {
        const float* src = red[w >> 1] + lane*52;
#pragma unroll
        for (int f = 0; f < 3; f++)
#pragma unroll
            for (int r = 0; r < 16; r++) of[f][r] += src[f*16 + r];
    }
    __syncthreads();
    if (w == 2) {
        float* dst = red[0] + lane*52;
#pragma unroll
        for (int f = 0; f < 3; f++)
#pragma unroll
            for (int r = 0; r < 16; r++) dst[f*16 + r] = of[f][r];
    }
    __syncthreads();
    if (w == 0) {
        const float* src = red[0] + lane*52;
#pragma unroll
        for (int f = 0; f < 3; f++)
#pragma unroll
            for (int r = 0; r < 16; r++) of[f][r] += src[f*16 + r];
        if (col == 20) {
#pragma unroll
            for (int r = 0; r < 16; r++) lred[qxmap(r, half)] = of[2][r];
        }
    }
    __syncthreads();
    if (w == 0) {
        float linv[16];
#pragma unroll
        for (int r = 0; r < 16; r++) linv[r] = 1.0f / lred[qxmap(r, half)];
#pragma unroll
        for (int f = 0; f < 3; f++) {
            int d = f*32 + col;
            if (d < DD) {
                int m = d >> 2, dd2 = d & 3;
#pragma unroll
                for (int r = 0; r < 16; r++) {
                    int q = qxmap(r, half);
                    size_t R = ((size_t)(b*NN + q0 + q))*21 + m;
                    Obuf[R*32 + h*4 + dd2] = of[f][r] * linv[r];
                }
            }
        }
    }
}

// ================ L5: output projection via MFMA (LDS-staged activations) ================
__global__ __launch_bounds__(256)
void proj_kernel(const float* __restrict__ Obuf, const float* __restrict__ Wp,
                 const float* __restrict__ bp, float* __restrict__ out)
{
    __shared__ ushort wps[1024];
    __shared__ float bps[32];
    __shared__ __align__(16) float os[128*36];
    int t = threadIdx.x;
    int w = t >> 6, lane = t & 63, col = lane & 31, half = lane >> 5;
    int R0 = blockIdx.x * 128;
    for (int i = t; i < 1024; i += 256) wps[i] = f2bf(Wp[i]);
    if (t < 32) bps[t] = bp[t];
    for (int i = t; i < 4096; i += 256)
        os[(i >> 5)*36 + (i & 31)] = Obuf[(size_t)R0*32 + i];
    __syncthreads();

    bf16x8 bw[2];
#pragma unroll
    for (int c = 0; c < 2; c++) {
        union { bf16x8 v; ushort s[8]; } u;
#pragma unroll
        for (int j = 0; j < 8; j++)
            u.s[j] = wps[(c*16 + half*8 + j)*32 + col];
        bw[c] = u.v;
    }
    bf16x8 aw[2];
#pragma unroll
    for (int c = 0; c < 2; c++) {
        const float* orr = os + (w*32 + col)*36 + c*16 + half*8;
        float4 v0 = *(const float4*)(orr);
        float4 v1 = *(const float4*)(orr + 4);
        union { bf16x8 v; ushort s[8]; } u;
        u.s[0]=f2bf(v0.x); u.s[1]=f2bf(v0.y); u.s[2]=f2bf(v0.z); u.s[3]=f2bf(v0.w);
        u.s[4]=f2bf(v1.x); u.s[5]=f2bf(v1.y); u.s[6]=f2bf(v1.z); u.s[7]=f2bf(v1.w);
        aw[c] = u.v;
    }
    f32x16 acc;
#pragma unroll
    for (int r = 0; r < 16; r++) acc[r] = 0.f;
#pragma unroll
    for (int c = 0; c < 2; c++)
        acc = __builtin_amdgcn_mfma_f32_32x32x16_bf16(aw[c], bw[c], acc, 0, 0, 0);
    float bb = bps[col];
#pragma unroll
    for (int r = 0; r < 16; r++)
        out[(size_t)(R0 + w*32 + qxmap(r, half))*32 + col] = acc[r] + bb;
}

extern "C" void kernel_launch(void* const* d_in, const int* in_sizes, int n_in,
                              void* d_out, int out_size, void* d_ws, size_t ws_size,
                              hipStream_t stream)
{
    const float* x     = (const float*)d_in[0];
    const float* Wqkv  = (const float*)d_in[1];
    const float* bqkv  = (const float*)d_in[2];
    const float* Wproj = (const float*)d_in[3];
    const float* bproj = (const float*)d_in[4];
    const float* Wsq   = (const float*)d_in[5];
    const float* bsq   = (const float*)d_in[6];
    const float* Wdw   = (const float*)d_in[7];
    const float* bdw   = (const float*)d_in[8];

    const size_t QP = (size_t)BN * NN * DP;   // 3,145,728
    const size_t VB = (size_t)BN * NN * DD;   // 2,752,512
    ushort* qf   = (ushort*)d_ws;
    ushort* kf   = qf + QP;
    ushort* vb   = kf + QP;
    ushort* vf   = vb + VB;
    float* Obuf  = (float*)(vf + QP);
    float* x2    = Obuf + VB;
    float* xw    = x2 + 32768;
    float* xp    = xw + 8192;
    float* btab  = xp + 8192;
    unsigned* Mg = (unsigned*)(btab + 3969*8);
    float* out   = (float*)d_out;

    l1_kernel  <<<736,        256, 0, stream>>>(x, Wqkv, bqkv, Wsq, bsq, qf, kf, vb, x2, Mg);
    l2_kernel  <<<544,        256, 0, stream>>>(vb, vf, x2, Wdw, bdw, xw, xp);
    bias_kernel<<<dim3(63,8), 512, 0, stream>>>(xw, xp, btab, Mg);
    attn_kernel<<<1024,       256, 0, stream>>>(qf, kf, vf, btab, Mg, Obuf);
    proj_kernel<<<NROWS/128,  256, 0, stream>>>(Obuf, Wproj, bproj, out);
}